// Round 8
// baseline (1009.647 us; speedup 1.0000x reference)
//
#include <hip/hip_runtime.h>
#include <cstddef>
#include <cstdint>

#define D_MODEL 1024
#define D_INNER 2048
#define DT_RANK 64
#define D_STATE 8
#define NLAYERS 4
#define BATCH 2
#define SEQ 1024
#define M_ROWS (BATCH*SEQ)   /* 2048 */
#define VOCAB 32000
#define XPAD 128             /* x_proj N padded 80 -> 128 */
#define NC 32                /* scan chunks */
#define LC 32                /* chunk length (NC*LC == SEQ) */
#define XSK 8                /* x_proj split-K factor */

typedef __attribute__((ext_vector_type(8))) short short8;
typedef __attribute__((ext_vector_type(4))) float f32x4;

#define GPTR(p) (const __attribute__((address_space(1))) void*)(p)
#define LPTR(p) (__attribute__((address_space(3))) void*)(p)

__device__ __forceinline__ float sigmoidf_(float x) { return 1.f / (1.f + __expf(-x)); }

__device__ __forceinline__ unsigned short f2bf(float f) {
    unsigned u = __float_as_uint(f);
    u += 0x7fffu + ((u >> 16) & 1u);         // round-to-nearest-even
    return (unsigned short)(u >> 16);
}
__device__ __forceinline__ float bf2f(unsigned short u) {
    return __uint_as_float((unsigned)u << 16);
}

// ---------------------------------------------------------------------------
// fp32 -> bf16 cast (contiguous), 4 elems/thread.
// ---------------------------------------------------------------------------
__global__ __launch_bounds__(256) void cast_kernel(const float* __restrict__ in,
                                                   unsigned short* __restrict__ out, int n4)
{
    int i = blockIdx.x * 256 + threadIdx.x;
    if (i >= n4) return;
    float4 v = ((const float4*)in)[i];
    ushort4 o;
    o.x = f2bf(v.x); o.y = f2bf(v.y); o.z = f2bf(v.z); o.w = f2bf(v.w);
    ((ushort4*)out)[i] = o;
}

// ---------------------------------------------------------------------------
// x_proj weight: cast 4x(80,2048) fp32 -> 4x(128,2048) bf16, rows 80..127 = 0
// ---------------------------------------------------------------------------
__global__ __launch_bounds__(256) void cast_pad_xproj(const float* __restrict__ in,
                                                      unsigned short* __restrict__ out)
{
    int i = blockIdx.x * 256 + threadIdx.x;     // over 4*128*2048/4 = 262144
    if (i >= NLAYERS * XPAD * D_INNER / 4) return;
    int col4 = i & (D_INNER / 4 - 1);           // 512 col-groups
    int row = (i >> 9) & (XPAD - 1);
    int layer = i >> 16;
    ushort4 o = {0, 0, 0, 0};
    if (row < 80) {
        float4 v = ((const float4*)(in + ((size_t)layer * 80 + row) * D_INNER))[col4];
        o.x = f2bf(v.x); o.y = f2bf(v.y); o.z = f2bf(v.z); o.w = f2bf(v.w);
    }
    ((ushort4*)out)[i] = o;
}

// ---------------------------------------------------------------------------
// Embedding gather -> x (fp32) and xb (bf16)
// ---------------------------------------------------------------------------
__global__ __launch_bounds__(256) void gather_kernel(const int* __restrict__ ids,
                                                     const float* __restrict__ embed,
                                                     float* __restrict__ x,
                                                     unsigned short* __restrict__ xb)
{
    int m = blockIdx.x;
    int t = threadIdx.x;
    int id = ids[m];
    float4 v = ((const float4*)(embed + (size_t)id * D_MODEL))[t];
    ((float4*)(x + (size_t)m * D_MODEL))[t] = v;
    ushort4 o;
    o.x = f2bf(v.x); o.y = f2bf(v.y); o.z = f2bf(v.z); o.w = f2bf(v.w);
    ((ushort4*)(xb + (size_t)m * D_MODEL))[t] = o;
}

// ---------------------------------------------------------------------------
// bf16 MFMA GEMM  C[M,N] = A[M,K] * B[N,K]^T
// 128x128 tile, BK=32, 4 waves. Double-buffered LDS, counted-vmcnt pipeline
// (T4): STAGE(next) -> vmcnt(4) -> s_barrier -> ds_read+MFMA -> s_barrier.
// T2 swizzle: 16B unit p = u ^ ((row>>1)&3); linear gload dest + inverse-
// swizzled global source (rule #21).
// EPI: 0 fp32 | 1 bf16 | 2 fp32 +bias | 3 bf16 softplus(v+bias)
// ---------------------------------------------------------------------------
template<int EPI>
__global__ __launch_bounds__(256) void gemm_bf16_nt(const unsigned short* __restrict__ A, int lda,
                                                    const unsigned short* __restrict__ B, int ldb,
                                                    void* __restrict__ Cv, int ldc,
                                                    int K, const float* __restrict__ bias)
{
    __shared__ unsigned short As[2][128 * 32];
    __shared__ unsigned short Bs[2][128 * 32];
    const int tid = threadIdx.x;

    const int gm = gridDim.x;
    const int bid = blockIdx.y * gm + blockIdx.x;
    const int q = (gm * gridDim.y) >> 3;           // nwg % 8 == 0 guaranteed
    const int swz = (bid & 7) * q + (bid >> 3);
    const int bm = (swz % gm) * 128, bn = (swz / gm) * 128;

    const int wid = tid >> 6, lane = tid & 63;
    const int wm = (wid >> 1) * 64, wn = (wid & 1) * 64;
    const int lrow = lane & 15, lkg = lane >> 4;

    const int srow = tid >> 2;                               // 0..63
    const int ksrc = ((tid & 3) ^ ((srow >> 1) & 3)) * 8;    // elems, const/thread
    const size_t kz = (size_t)blockIdx.z * K;
    const unsigned short* Ag = A + (size_t)(bm + srow) * lda + kz + ksrc;
    const unsigned short* Bg = B + (size_t)(bn + srow) * ldb + kz + ksrc;
    const size_t r64a = (size_t)64 * lda;
    const size_t r64b = (size_t)64 * ldb;

#define STAGE(buf, koff)                                                                              \
    do {                                                                                              \
        __builtin_amdgcn_global_load_lds(GPTR(Ag + (koff)),        LPTR(&As[buf][tid * 8]), 16, 0, 0);\
        __builtin_amdgcn_global_load_lds(GPTR(Ag + r64a + (koff)), LPTR(&As[buf][2048 + tid * 8]), 16, 0, 0);\
        __builtin_amdgcn_global_load_lds(GPTR(Bg + (koff)),        LPTR(&Bs[buf][tid * 8]), 16, 0, 0);\
        __builtin_amdgcn_global_load_lds(GPTR(Bg + r64b + (koff)), LPTR(&Bs[buf][2048 + tid * 8]), 16, 0, 0);\
    } while (0)

    f32x4 acc[4][4];
    #pragma unroll
    for (int i = 0; i < 4; ++i)
        #pragma unroll
        for (int j = 0; j < 4; ++j)
            acc[i][j] = f32x4{0.f, 0.f, 0.f, 0.f};

    STAGE(0, 0);                      // prologue

    int cur = 0;
    for (int k0 = 0; k0 < K; k0 += 32) {
        if (k0 + 32 < K) {
            STAGE(cur ^ 1, k0 + 32);                             // next tile in flight
            asm volatile("s_waitcnt vmcnt(4)" ::: "memory");     // cur's 4 landed
        } else {
            asm volatile("s_waitcnt vmcnt(0)" ::: "memory");     // final drain
        }
        __builtin_amdgcn_s_barrier();          // publish cur to all waves
        __builtin_amdgcn_sched_barrier(0);     // pin: no hoisting above the wait

        short8 af[4], bf[4];
        #pragma unroll
        for (int i = 0; i < 4; ++i) {
            int ra = wm + 16 * i + lrow;
            int pa = lkg ^ ((ra >> 1) & 3);
            af[i] = *(const short8*)(&As[cur][ra * 32 + pa * 8]);
            int rb = wn + 16 * i + lrow;
            int pb = lkg ^ ((rb >> 1) & 3);
            bf[i] = *(const short8*)(&Bs[cur][rb * 32 + pb * 8]);
        }
        __builtin_amdgcn_s_setprio(1);
        #pragma unroll
        for (int i = 0; i < 4; ++i)
            #pragma unroll
            for (int j = 0; j < 4; ++j)
                acc[i][j] = __builtin_amdgcn_mfma_f32_16x16x32_bf16(af[i], bf[j], acc[i][j], 0, 0, 0);
        __builtin_amdgcn_s_setprio(0);

        __builtin_amdgcn_s_barrier();          // all reads of cur done before overwrite
        cur ^= 1;
    }
#undef STAGE

    const int crow = bm + wm + lkg * 4;
    const int ccol = bn + wn + lrow;
    #pragma unroll
    for (int i = 0; i < 4; ++i) {
        #pragma unroll
        for (int j = 0; j < 4; ++j) {
            float bv = (EPI == 2 || EPI == 3) ? bias[ccol + 16 * j] : 0.f;
            #pragma unroll
            for (int r = 0; r < 4; ++r) {
                float v = acc[i][j][r] + bv;
                size_t off = (size_t)(crow + 16 * i + r) * ldc + ccol + 16 * j;
                if (EPI == 0) {
                    ((float*)Cv)[(size_t)blockIdx.z * M_ROWS * ldc + off] = v;
                } else if (EPI == 2) {
                    ((float*)Cv)[off] = v;
                } else {
                    if (EPI == 3) v = (v > 20.f) ? v : log1pf(__expf(v));
                    ((unsigned short*)Cv)[off] = f2bf(v);
                }
            }
        }
    }
}

// ---------------------------------------------------------------------------
// 256x256-tile variant for the vocab GEMM: 512 thr = 8 waves (2M x 4N),
// BK=32, 64 KiB double-buffered LDS, counted-vmcnt schedule & T2 swizzle.
// EPI 2 only: fp32 out +bias.
// ---------------------------------------------------------------------------
__global__ __launch_bounds__(512) void gemm_bf16_nt256(const unsigned short* __restrict__ A, int lda,
                                                       const unsigned short* __restrict__ B, int ldb,
                                                       float* __restrict__ C, int ldc,
                                                       int K, const float* __restrict__ bias)
{
    __shared__ unsigned short As[2][256 * 32];
    __shared__ unsigned short Bs[2][256 * 32];
    const int tid = threadIdx.x;

    const int gm = gridDim.x;
    const int bid = blockIdx.y * gm + blockIdx.x;
    const int q = (gm * gridDim.y) >> 3;
    const int swz = (bid & 7) * q + (bid >> 3);
    const int bm = (swz % gm) * 256, bn = (swz / gm) * 256;

    const int wid = tid >> 6, lane = tid & 63;
    const int wm = (wid >> 2) * 128, wn = (wid & 3) * 64;
    const int lrow = lane & 15, lkg = lane >> 4;

    const int srow = tid >> 2;                               // 0..127
    const int ksrc = ((tid & 3) ^ ((srow >> 1) & 3)) * 8;
    const unsigned short* Ag = A + (size_t)(bm + srow) * lda + ksrc;
    const unsigned short* Bg = B + (size_t)(bn + srow) * ldb + ksrc;
    const size_t r128a = (size_t)128 * lda;
    const size_t r128b = (size_t)128 * ldb;

#define STAGE2(buf, koff)                                                                               \
    do {                                                                                                \
        __builtin_amdgcn_global_load_lds(GPTR(Ag + (koff)),         LPTR(&As[buf][tid * 8]), 16, 0, 0); \
        __builtin_amdgcn_global_load_lds(GPTR(Ag + r128a + (koff)), LPTR(&As[buf][4096 + tid * 8]), 16, 0, 0);\
        __builtin_amdgcn_global_load_lds(GPTR(Bg + (koff)),         LPTR(&Bs[buf][tid * 8]), 16, 0, 0); \
        __builtin_amdgcn_global_load_lds(GPTR(Bg + r128b + (koff)), LPTR(&Bs[buf][4096 + tid * 8]), 16, 0, 0);\
    } while (0)

    f32x4 acc[8][4];
    #pragma unroll
    for (int i = 0; i < 8; ++i)
        #pragma unroll
        for (int j = 0; j < 4; ++j)
            acc[i][j] = f32x4{0.f, 0.f, 0.f, 0.f};

    STAGE2(0, 0);

    int cur = 0;
    for (int k0 = 0; k0 < K; k0 += 32) {
        if (k0 + 32 < K) {
            STAGE2(cur ^ 1, k0 + 32);
            asm volatile("s_waitcnt vmcnt(4)" ::: "memory");
        } else {
            asm volatile("s_waitcnt vmcnt(0)" ::: "memory");
        }
        __builtin_amdgcn_s_barrier();
        __builtin_amdgcn_sched_barrier(0);

        short8 af[8], bf[4];
        #pragma unroll
        for (int j = 0; j < 4; ++j) {
            int rb = wn + 16 * j + lrow;
            int pb = lkg ^ ((rb >> 1) & 3);
            bf[j] = *(const short8*)(&Bs[cur][rb * 32 + pb * 8]);
        }
        #pragma unroll
        for (int i = 0; i < 8; ++i) {
            int ra = wm + 16 * i + lrow;
            int pa = lkg ^ ((ra >> 1) & 3);
            af[i] = *(const short8*)(&As[cur][ra * 32 + pa * 8]);
        }
        __builtin_amdgcn_s_setprio(1);
        #pragma unroll
        for (int i = 0; i < 8; ++i)
            #pragma unroll
            for (int j = 0; j < 4; ++j)
                acc[i][j] = __builtin_amdgcn_mfma_f32_16x16x32_bf16(af[i], bf[j], acc[i][j], 0, 0, 0);
        __builtin_amdgcn_s_setprio(0);

        __builtin_amdgcn_s_barrier();
        cur ^= 1;
    }
#undef STAGE2

    const int crow = bm + wm + lkg * 4;
    const int ccol = bn + wn + lrow;
    #pragma unroll
    for (int i = 0; i < 8; ++i) {
        #pragma unroll
        for (int j = 0; j < 4; ++j) {
            float bv = bias[ccol + 16 * j];
            float* Cp = C + (size_t)(crow + 16 * i) * ldc + ccol + 16 * j;
            #pragma unroll
            for (int r = 0; r < 4; ++r)
                Cp[(size_t)r * ldc] = acc[i][j][r] + bv;
        }
    }
}

// ---------------------------------------------------------------------------
// Reduce XSK split-K partials -> xdbl (fp32) + xdbl_b (bf16)
// ---------------------------------------------------------------------------
__global__ __launch_bounds__(256) void reduce_xdbl(const float* __restrict__ part,
                                                   float* __restrict__ xdbl,
                                                   unsigned short* __restrict__ xdbl_b)
{
    int i = blockIdx.x * 256 + threadIdx.x;     // over 2048*128/4 = 65536
    float4 s = ((const float4*)part)[i];
    #pragma unroll
    for (int z = 1; z < XSK; ++z) {
        float4 v = ((const float4*)part)[(size_t)z * (M_ROWS * XPAD / 4) + i];
        s.x += v.x; s.y += v.y; s.z += v.z; s.w += v.w;
    }
    ((float4*)xdbl)[i] = s;
    ushort4 o;
    o.x = f2bf(s.x); o.y = f2bf(s.y); o.z = f2bf(s.z); o.w = f2bf(s.w);
    ((ushort4*)xdbl_b)[i] = o;
}

// ---------------------------------------------------------------------------
// Causal depthwise conv1d (k=4) + bias + SiLU; bf16 in (xzb) -> bf16 out (xcb)
// ---------------------------------------------------------------------------
__global__ __launch_bounds__(256) void conv_silu_kernel(const unsigned short* __restrict__ xzb,
                                                        const float* __restrict__ cw,
                                                        const float* __restrict__ cb,
                                                        unsigned short* __restrict__ xcb)
{
    int idx = blockIdx.x * 256 + threadIdx.x;
    int d = idx & (D_INNER - 1);
    int m = idx >> 11;
    int l = m & (SEQ - 1);
    int b = m >> 10;
    float w0 = cw[d * 4 + 0], w1 = cw[d * 4 + 1], w2 = cw[d * 4 + 2], w3 = cw[d * 4 + 3];
    float s = cb[d];
    const unsigned short* base = xzb + ((size_t)b * SEQ) * (2 * D_INNER) + d;
    if (l - 3 >= 0) s += bf2f(base[(size_t)(l - 3) * (2 * D_INNER)]) * w0;
    if (l - 2 >= 0) s += bf2f(base[(size_t)(l - 2) * (2 * D_INNER)]) * w1;
    if (l - 1 >= 0) s += bf2f(base[(size_t)(l - 1) * (2 * D_INNER)]) * w2;
    s += bf2f(base[(size_t)l * (2 * D_INNER)]) * w3;
    float v = s * sigmoidf_(s);
    xcb[(size_t)m * D_INNER + d] = f2bf(v);
}

// ---------------------------------------------------------------------------
// Chunk-parallel selective scan (linear recurrence decomposition).
// dt, xc, z in bf16; B/C from fp32 xdbl; H/P fp32; math fp32.
// ---------------------------------------------------------------------------
__global__ __launch_bounds__(256) void scan_partial(const unsigned short* __restrict__ dtb,
                                                    const float* __restrict__ xdbl,
                                                    const unsigned short* __restrict__ xcb,
                                                    const float* __restrict__ A_log,
                                                    float* __restrict__ H,
                                                    float* __restrict__ P)
{
    const int tid = threadIdx.x;
    const int b = blockIdx.x & 1;
    const int c = (blockIdx.x >> 1) & (NC - 1);
    const int d = ((blockIdx.x >> 6) << 8) + tid;

    __shared__ float Bsm[LC][8];
    {
        int r = tid >> 3, n = tid & 7;
        Bsm[r][n] = xdbl[(size_t)(b * SEQ + c * LC + r) * XPAD + DT_RANK + n];
    }
    __syncthreads();

    float An[8];
    #pragma unroll
    for (int n = 0; n < 8; ++n) An[n] = -__expf(A_log[d * 8 + n]);
    float h[8] = {0.f,0.f,0.f,0.f,0.f,0.f,0.f,0.f};
    float p[8] = {1.f,1.f,1.f,1.f,1.f,1.f,1.f,1.f};

    const unsigned short* dtp = dtb + (size_t)(b * SEQ + c * LC) * D_INNER + d;
    const unsigned short* xcp = xcb + (size_t)(b * SEQ + c * LC) * D_INNER + d;
    for (int l = 0; l < LC; ++l) {
        float dtv = bf2f(dtp[(size_t)l * D_INNER]);
        float ux  = dtv * bf2f(xcp[(size_t)l * D_INNER]);
        #pragma unroll
        for (int n = 0; n < 8; ++n) {
            float dA = __expf(dtv * An[n]);
            h[n] = dA * h[n] + Bsm[l][n] * ux;
            p[n] *= dA;
        }
    }
    size_t base = (size_t)((b * NC + c) * 8) * D_INNER + d;
    #pragma unroll
    for (int n = 0; n < 8; ++n) {
        H[base + (size_t)n * D_INNER] = h[n];
        P[base + (size_t)n * D_INNER] = p[n];
    }
}

__global__ __launch_bounds__(256) void scan_combine(const float* __restrict__ H,
                                                    float* __restrict__ P /* -> h0 */)
{
    int idx = blockIdx.x * 256 + threadIdx.x;   // 32768 = 2*8*2048
    int d = idx & (D_INNER - 1);
    int n = (idx >> 11) & 7;
    int b = idx >> 14;
    float hp = 0.f;
    for (int c = 0; c < NC; ++c) {
        size_t base = (size_t)((b * NC + c) * 8 + n) * D_INNER + d;
        float Pv = P[base], Hv = H[base];
        P[base] = hp;
        hp = Pv * hp + Hv;
    }
}

__global__ __launch_bounds__(256) void scan_final(const unsigned short* __restrict__ dtb,
                                                  const float* __restrict__ xdbl,
                                                  const unsigned short* __restrict__ xcb,
                                                  const unsigned short* __restrict__ xzb,
                                                  const float* __restrict__ A_log,
                                                  const float* __restrict__ Dp,
                                                  const float* __restrict__ h0,
                                                  unsigned short* __restrict__ yb)
{
    const int tid = threadIdx.x;
    const int b = blockIdx.x & 1;
    const int c = (blockIdx.x >> 1) & (NC - 1);
    const int d = ((blockIdx.x >> 6) << 8) + tid;

    __shared__ float Bsm[LC][8];
    __shared__ float Csm[LC][8];
    {
        int r = tid >> 3, n = tid & 7;
        size_t xrow = (size_t)(b * SEQ + c * LC + r) * XPAD;
        Bsm[r][n] = xdbl[xrow + DT_RANK + n];
        Csm[r][n] = xdbl[xrow + DT_RANK + 8 + n];
    }
    __syncthreads();

    float An[8], h[8];
    size_t base = (size_t)((b * NC + c) * 8) * D_INNER + d;
    #pragma unroll
    for (int n = 0; n < 8; ++n) {
        An[n] = -__expf(A_log[d * 8 + n]);
        h[n] = h0[base + (size_t)n * D_INNER];
    }
    const float Dv = Dp[d];

    const unsigned short* dtp = dtb + (size_t)(b * SEQ + c * LC) * D_INNER + d;
    const unsigned short* xcp = xcb + (size_t)(b * SEQ + c * LC) * D_INNER + d;
    const unsigned short* zp  = xzb + (size_t)(b * SEQ + c * LC) * (2 * D_INNER) + D_INNER + d;
    unsigned short* ybp = yb + (size_t)(b * SEQ + c * LC) * D_INNER + d;

    for (int l = 0; l < LC; ++l) {
        float dtv = bf2f(dtp[(size_t)l * D_INNER]);
        float xcv = bf2f(xcp[(size_t)l * D_INNER]);
        float zv  = bf2f(zp[(size_t)l * (2 * D_INNER)]);
        float ux = dtv * xcv;
        float acc = 0.f;
        #pragma unroll
        for (int n = 0; n < 8; ++n) {
            float dA = __expf(dtv * An[n]);
            h[n] = dA * h[n] + Bsm[l][n] * ux;
            acc += h[n] * Csm[l][n];
        }
        float yv = (acc + xcv * Dv) * (zv * sigmoidf_(zv));
        ybp[(size_t)l * D_INNER] = f2bf(yv);
    }
}

// ---------------------------------------------------------------------------
// LayerNorm (1024). ADD: out = LN(extra + xin) else LN(xin). Emits fp32 + bf16.
// ---------------------------------------------------------------------------
template<bool ADD>
__global__ __launch_bounds__(256) void ln_kernel(const float* __restrict__ extra,
                                                 const float* __restrict__ xin,
                                                 float* __restrict__ xout,
                                                 unsigned short* __restrict__ xbout,
                                                 const float* __restrict__ g,
                                                 const float* __restrict__ bb)
{
    int m = blockIdx.x;
    int t = threadIdx.x;
    float4 v = ((const float4*)(xin + (size_t)m * D_MODEL))[t];
    if (ADD) {
        float4 e = ((const float4*)(extra + (size_t)m * D_MODEL))[t];
        v.x += e.x; v.y += e.y; v.z += e.z; v.w += e.w;
    }
    float s  = v.x + v.y + v.z + v.w;
    float s2 = v.x * v.x + v.y * v.y + v.z * v.z + v.w * v.w;
    for (int off = 32; off; off >>= 1) {
        s  += __shfl_down(s, off);
        s2 += __shfl_down(s2, off);
    }
    __shared__ float red[8];
    int wid = t >> 6, lane = t & 63;
    if (lane == 0) { red[wid] = s; red[wid + 4] = s2; }
    __syncthreads();
    if (t == 0) {
        float a  = red[0] + red[1] + red[2] + red[3];
        float b2 = red[4] + red[5] + red[6] + red[7];
        float mu = a * (1.f / D_MODEL);
        red[0] = mu;
        red[4] = b2 * (1.f / D_MODEL) - mu * mu;
    }
    __syncthreads();
    float mu = red[0];
    float rs = rsqrtf(red[4] + 1e-5f);
    float4 gg = ((const float4*)g)[t];
    float4 bv = ((const float4*)bb)[t];
    float4 o;
    o.x = (v.x - mu) * rs * gg.x + bv.x;
    o.y = (v.y - mu) * rs * gg.y + bv.y;
    o.z = (v.z - mu) * rs * gg.z + bv.z;
    o.w = (v.w - mu) * rs * gg.w + bv.w;
    ((float4*)(xout + (size_t)m * D_MODEL))[t] = o;
    ushort4 ob;
    ob.x = f2bf(o.x); ob.y = f2bf(o.y); ob.z = f2bf(o.z); ob.w = f2bf(o.w);
    ((ushort4*)(xbout + (size_t)m * D_MODEL))[t] = ob;
}

// ---------------------------------------------------------------------------
extern "C" void kernel_launch(void* const* d_in, const int* in_sizes, int n_in,
                              void* d_out, int out_size, void* d_ws, size_t ws_size,
                              hipStream_t stream)
{
    const int*   ids      = (const int*)d_in[0];
    const float* embed    = (const float*)d_in[1];
    const float* in_proj  = (const float*)d_in[2];
    const float* conv_w   = (const float*)d_in[3];
    const float* conv_b   = (const float*)d_in[4];
    const float* x_proj   = (const float*)d_in[5];
    const float* dt_w     = (const float*)d_in[6];
    const float* dt_b     = (const float*)d_in[7];
    const float* A_log    = (const float*)d_in[8];
    const float* Dp       = (const float*)d_in[9];
    const float* out_proj = (const float*)d_in[10];
    const float* ln_g     = (const float*)d_in[11];
    const float* ln_b     = (const float*)d_in[12];
    const float* fn_g     = (const float*)d_in[13];
    const float* fn_b     = (const float*)d_in[14];
    const float* fc_w     = (const float*)d_in[15];
    const float* fc_b     = (const float*)d_in[16];
    float* logits = (float*)d_out;

    // ---- workspace layout (fp32 first, then bf16) ----
    float* ws = (float*)d_ws;
    float* x     = ws;                                   // 2048*1024
    float* xdbl  = x + (size_t)M_ROWS * D_MODEL;         // 2048*128
    float* tmp   = xdbl + (size_t)M_ROWS * XPAD;         // 2048*1024 (H/P alias)
    float* xpart = tmp + (size_t)M_ROWS * D_MODEL;       // XSK*2048*128

    float* Hbuf = tmp;
    float* Pbuf = tmp + (size_t)BATCH * NC * D_STATE * D_INNER;

    unsigned short* xb     = (unsigned short*)(xpart + (size_t)XSK * M_ROWS * XPAD);
    unsigned short* yb     = xb + (size_t)M_ROWS * D_MODEL;
    unsigned short* xzb    = yb + (size_t)M_ROWS * D_INNER;
    unsigned short* xcb    = xzb + (size_t)M_ROWS * 2 * D_INNER;
    unsigned short* dtb    = xcb + (size_t)M_ROWS * D_INNER;
    unsigned short* xdbl_b = dtb + (size_t)M_ROWS * D_INNER;
    unsigned short* wb_in  = xdbl_b + (size_t)M_ROWS * XPAD;
    unsigned short* wb_out = wb_in + (size_t)NLAYERS * 2 * D_INNER * D_MODEL;
    unsigned short* wb_fc  = wb_out + (size_t)NLAYERS * D_MODEL * D_INNER;
    unsigned short* wb_x   = wb_fc + (size_t)VOCAB * D_MODEL;
    unsigned short* wb_dt  = wb_x + (size_t)NLAYERS * XPAD * D_INNER;

    // ---- weight casts ----
    {
        int n4 = NLAYERS * 2 * D_INNER * D_MODEL / 4;
        cast_kernel<<<(n4 + 255) / 256, 256, 0, stream>>>(in_proj, wb_in, n4);
        n4 = NLAYERS * D_MODEL * D_INNER / 4;
        cast_kernel<<<(n4 + 255) / 256, 256, 0, stream>>>(out_proj, wb_out, n4);
        n4 = VOCAB * D_MODEL / 4;
        cast_kernel<<<(n4 + 255) / 256, 256, 0, stream>>>(fc_w, wb_fc, n4);
        n4 = NLAYERS * D_INNER * DT_RANK / 4;
        cast_kernel<<<(n4 + 255) / 256, 256, 0, stream>>>(dt_w, wb_dt, n4);
        n4 = NLAYERS * XPAD * D_INNER / 4;
        cast_pad_xproj<<<(n4 + 255) / 256, 256, 0, stream>>>(x_proj, wb_x);
    }

    // ---- embedding (fp32 + bf16) ----
    gather_kernel<<<M_ROWS, 256, 0, stream>>>(ids, embed, x, xb);

    for (int i = 0; i < NLAYERS; ++i) {
        const unsigned short* W_in_b  = wb_in + (size_t)i * 2 * D_INNER * D_MODEL;
        const unsigned short* W_out_b = wb_out + (size_t)i * D_MODEL * D_INNER;
        const unsigned short* W_x_b   = wb_x + (size_t)i * XPAD * D_INNER;
        const unsigned short* W_dt_b  = wb_dt + (size_t)i * D_INNER * DT_RANK;
        const float* cw    = conv_w + (size_t)i * D_INNER * 4;
        const float* cb    = conv_b + (size_t)i * D_INNER;
        const float* b_dt  = dt_b + (size_t)i * D_INNER;
        const float* Al    = A_log + (size_t)i * D_INNER * D_STATE;
        const float* Dl    = Dp + (size_t)i * D_INNER;
        const float* g     = ln_g + (size_t)i * D_MODEL;
        const float* bb    = ln_b + (size_t)i * D_MODEL;

        // xz(bf16) = x @ in_proj^T   (2048 x 4096, K=1024)   grid 16x32
        gemm_bf16_nt<1><<<dim3(M_ROWS / 128, 2 * D_INNER / 128), 256, 0, stream>>>(
            xb, D_MODEL, W_in_b, D_MODEL, xzb, 2 * D_INNER, D_MODEL, nullptr);

        // xc(bf16) = silu(conv(xz[:, :2048]) + cb)
        conv_silu_kernel<<<(M_ROWS * D_INNER) / 256, 256, 0, stream>>>(xzb, cw, cb, xcb);

        // x_dbl partials: (2048 x 128, K=2048 split XSK x 256)  grid 16x1x8
        gemm_bf16_nt<0><<<dim3(M_ROWS / 128, 1, XSK), 256, 0, stream>>>(
            xcb, D_INNER, W_x_b, D_INNER, xpart, XPAD, D_INNER / XSK, nullptr);
        reduce_xdbl<<<(M_ROWS * XPAD / 4) / 256, 256, 0, stream>>>(xpart, xdbl, xdbl_b);

        // dt(bf16) = softplus(x_dbl[:, :64] @ dt_w^T + b_dt)  (2048x2048, K=64) grid 16x16
        gemm_bf16_nt<3><<<dim3(M_ROWS / 128, D_INNER / 128), 256, 0, stream>>>(
            xdbl_b, XPAD, W_dt_b, DT_RANK, dtb, D_INNER, DT_RANK, b_dt);

        // chunk-parallel scan -> yb (bf16)
        scan_partial<<<BATCH * NC * (D_INNER / 256), 256, 0, stream>>>(
            dtb, xdbl, xcb, Al, Hbuf, Pbuf);
        scan_combine<<<(BATCH * D_STATE * D_INNER) / 256, 256, 0, stream>>>(Hbuf, Pbuf);
        scan_final<<<BATCH * NC * (D_INNER / 256), 256, 0, stream>>>(
            dtb, xdbl, xcb, xzb, Al, Dl, Pbuf, yb);

        // tmp(fp32) = y @ out_proj^T   (2048 x 1024, K=2048)   grid 16x8
        gemm_bf16_nt<0><<<dim3(M_ROWS / 128, D_MODEL / 128), 256, 0, stream>>>(
            yb, D_INNER, W_out_b, D_INNER, tmp, D_MODEL, D_INNER, nullptr);

        // x = LN(tmp + x)  (fp32 + bf16)
        ln_kernel<true><<<M_ROWS, 256, 0, stream>>>(tmp, x, x, xb, g, bb);
    }

    // final LN -> tmp + xb
    ln_kernel<false><<<M_ROWS, 256, 0, stream>>>(nullptr, x, tmp, xb, fn_g, fn_b);

    // logits = xf @ fc_w^T + fc_b   (2048 x 32000, K=1024)   grid 8x125, 512 thr
    gemm_bf16_nt256<<<dim3(M_ROWS / 256, VOCAB / 256), 512, 0, stream>>>(
        xb, D_MODEL, wb_fc, D_MODEL, logits, VOCAB, D_MODEL, fc_b);
}

// Round 9
// 1002.218 us; speedup vs baseline: 1.0074x; 1.0074x over previous
//
#include <hip/hip_runtime.h>
#include <cstddef>
#include <cstdint>

#define D_MODEL 1024
#define D_INNER 2048
#define DT_RANK 64
#define D_STATE 8
#define NLAYERS 4
#define BATCH 2
#define SEQ 1024
#define M_ROWS (BATCH*SEQ)   /* 2048 */
#define VOCAB 32000
#define XPAD 128             /* x_proj N padded 80 -> 128 */
#define NC 32                /* scan chunks */
#define LC 32                /* chunk length (NC*LC == SEQ) */
#define XSK 8                /* x_proj split-K factor */

typedef __attribute__((ext_vector_type(8))) short short8;
typedef __attribute__((ext_vector_type(4))) float f32x4;

#define GPTR(p) (const __attribute__((address_space(1))) void*)(p)
#define LPTR(p) (__attribute__((address_space(3))) void*)(p)

__device__ __forceinline__ float sigmoidf_(float x) { return 1.f / (1.f + __expf(-x)); }

__device__ __forceinline__ unsigned short f2bf(float f) {
    unsigned u = __float_as_uint(f);
    u += 0x7fffu + ((u >> 16) & 1u);         // round-to-nearest-even
    return (unsigned short)(u >> 16);
}
__device__ __forceinline__ float bf2f(unsigned short u) {
    return __uint_as_float((unsigned)u << 16);
}

// ---------------------------------------------------------------------------
// fp32 -> bf16 cast (contiguous), 4 elems/thread.
// ---------------------------------------------------------------------------
__global__ __launch_bounds__(256) void cast_kernel(const float* __restrict__ in,
                                                   unsigned short* __restrict__ out, int n4)
{
    int i = blockIdx.x * 256 + threadIdx.x;
    if (i >= n4) return;
    float4 v = ((const float4*)in)[i];
    ushort4 o;
    o.x = f2bf(v.x); o.y = f2bf(v.y); o.z = f2bf(v.z); o.w = f2bf(v.w);
    ((ushort4*)out)[i] = o;
}

// ---------------------------------------------------------------------------
// x_proj weight: cast 4x(80,2048) fp32 -> 4x(128,2048) bf16, rows 80..127 = 0
// ---------------------------------------------------------------------------
__global__ __launch_bounds__(256) void cast_pad_xproj(const float* __restrict__ in,
                                                      unsigned short* __restrict__ out)
{
    int i = blockIdx.x * 256 + threadIdx.x;     // over 4*128*2048/4 = 262144
    if (i >= NLAYERS * XPAD * D_INNER / 4) return;
    int col4 = i & (D_INNER / 4 - 1);           // 512 col-groups
    int row = (i >> 9) & (XPAD - 1);
    int layer = i >> 16;
    ushort4 o = {0, 0, 0, 0};
    if (row < 80) {
        float4 v = ((const float4*)(in + ((size_t)layer * 80 + row) * D_INNER))[col4];
        o.x = f2bf(v.x); o.y = f2bf(v.y); o.z = f2bf(v.z); o.w = f2bf(v.w);
    }
    ((ushort4*)out)[i] = o;
}

// ---------------------------------------------------------------------------
// Embedding gather -> x (fp32) and xb (bf16)
// ---------------------------------------------------------------------------
__global__ __launch_bounds__(256) void gather_kernel(const int* __restrict__ ids,
                                                     const float* __restrict__ embed,
                                                     float* __restrict__ x,
                                                     unsigned short* __restrict__ xb)
{
    int m = blockIdx.x;
    int t = threadIdx.x;
    int id = ids[m];
    float4 v = ((const float4*)(embed + (size_t)id * D_MODEL))[t];
    ((float4*)(x + (size_t)m * D_MODEL))[t] = v;
    ushort4 o;
    o.x = f2bf(v.x); o.y = f2bf(v.y); o.z = f2bf(v.z); o.w = f2bf(v.w);
    ((ushort4*)(xb + (size_t)m * D_MODEL))[t] = o;
}

// ---------------------------------------------------------------------------
// bf16 MFMA GEMM  C[M,N] = A[M,K] * B[N,K]^T
// 128x128 tile, BK=32, 4 waves. Double-buffered LDS, counted-vmcnt pipeline.
// EPI: 0 fp32 (+splitK z-offset) | 1 bf16 | 2 fp32 +bias | 3 bf16 softplus(v+bias)
// ---------------------------------------------------------------------------
template<int EPI>
__global__ __launch_bounds__(256) void gemm_bf16_nt(const unsigned short* __restrict__ A, int lda,
                                                    const unsigned short* __restrict__ B, int ldb,
                                                    void* __restrict__ Cv, int ldc,
                                                    int K, const float* __restrict__ bias)
{
    __shared__ unsigned short As[2][128 * 32];
    __shared__ unsigned short Bs[2][128 * 32];
    const int tid = threadIdx.x;

    const int gm = gridDim.x;
    const int bid = blockIdx.y * gm + blockIdx.x;
    const int q = (gm * gridDim.y) >> 3;           // nwg % 8 == 0 guaranteed
    const int swz = (bid & 7) * q + (bid >> 3);
    const int bm = (swz % gm) * 128, bn = (swz / gm) * 128;

    const int wid = tid >> 6, lane = tid & 63;
    const int wm = (wid >> 1) * 64, wn = (wid & 1) * 64;
    const int lrow = lane & 15, lkg = lane >> 4;

    const int srow = tid >> 2;                               // 0..63
    const int ksrc = ((tid & 3) ^ ((srow >> 1) & 3)) * 8;    // elems, const/thread
    const size_t kz = (size_t)blockIdx.z * K;
    const unsigned short* Ag = A + (size_t)(bm + srow) * lda + kz + ksrc;
    const unsigned short* Bg = B + (size_t)(bn + srow) * ldb + kz + ksrc;
    const size_t r64a = (size_t)64 * lda;
    const size_t r64b = (size_t)64 * ldb;

#define STAGE(buf, koff)                                                                              \
    do {                                                                                              \
        __builtin_amdgcn_global_load_lds(GPTR(Ag + (koff)),        LPTR(&As[buf][tid * 8]), 16, 0, 0);\
        __builtin_amdgcn_global_load_lds(GPTR(Ag + r64a + (koff)), LPTR(&As[buf][2048 + tid * 8]), 16, 0, 0);\
        __builtin_amdgcn_global_load_lds(GPTR(Bg + (koff)),        LPTR(&Bs[buf][tid * 8]), 16, 0, 0);\
        __builtin_amdgcn_global_load_lds(GPTR(Bg + r64b + (koff)), LPTR(&Bs[buf][2048 + tid * 8]), 16, 0, 0);\
    } while (0)

    f32x4 acc[4][4];
    #pragma unroll
    for (int i = 0; i < 4; ++i)
        #pragma unroll
        for (int j = 0; j < 4; ++j)
            acc[i][j] = f32x4{0.f, 0.f, 0.f, 0.f};

    STAGE(0, 0);                      // prologue

    int cur = 0;
    for (int k0 = 0; k0 < K; k0 += 32) {
        if (k0 + 32 < K) {
            STAGE(cur ^ 1, k0 + 32);                             // next tile in flight
            asm volatile("s_waitcnt vmcnt(4)" ::: "memory");     // cur's 4 landed
        } else {
            asm volatile("s_waitcnt vmcnt(0)" ::: "memory");     // final drain
        }
        __builtin_amdgcn_s_barrier();          // publish cur to all waves
        __builtin_amdgcn_sched_barrier(0);     // pin: no hoisting above the wait

        short8 af[4], bf[4];
        #pragma unroll
        for (int i = 0; i < 4; ++i) {
            int ra = wm + 16 * i + lrow;
            int pa = lkg ^ ((ra >> 1) & 3);
            af[i] = *(const short8*)(&As[cur][ra * 32 + pa * 8]);
            int rb = wn + 16 * i + lrow;
            int pb = lkg ^ ((rb >> 1) & 3);
            bf[i] = *(const short8*)(&Bs[cur][rb * 32 + pb * 8]);
        }
        __builtin_amdgcn_s_setprio(1);
        #pragma unroll
        for (int i = 0; i < 4; ++i)
            #pragma unroll
            for (int j = 0; j < 4; ++j)
                acc[i][j] = __builtin_amdgcn_mfma_f32_16x16x32_bf16(af[i], bf[j], acc[i][j], 0, 0, 0);
        __builtin_amdgcn_s_setprio(0);

        __builtin_amdgcn_s_barrier();          // all reads of cur done before overwrite
        cur ^= 1;
    }
#undef STAGE

    const int crow = bm + wm + lkg * 4;
    const int ccol = bn + wn + lrow;
    #pragma unroll
    for (int i = 0; i < 4; ++i) {
        #pragma unroll
        for (int j = 0; j < 4; ++j) {
            float bv = (EPI == 2 || EPI == 3) ? bias[ccol + 16 * j] : 0.f;
            #pragma unroll
            for (int r = 0; r < 4; ++r) {
                float v = acc[i][j][r] + bv;
                size_t off = (size_t)(crow + 16 * i + r) * ldc + ccol + 16 * j;
                if (EPI == 0) {
                    ((float*)Cv)[(size_t)blockIdx.z * M_ROWS * ldc + off] = v;
                } else if (EPI == 2) {
                    ((float*)Cv)[off] = v;
                } else {
                    if (EPI == 3) v = (v > 20.f) ? v : log1pf(__expf(v));
                    ((unsigned short*)Cv)[off] = f2bf(v);
                }
            }
        }
    }
}

// ---------------------------------------------------------------------------
// 8-phase 256x256 GEMM (m201 template, plain HIP) — vocab projection.
// 512 thr = 8 waves (2M x 4N); BK=64; LDS 128 KiB (2 dbuf x 256x64 x A,B).
// Per K-tile (4 phases): quadrant MFMA(16) with {ds_read || stage-issue ->
// barrier -> MFMA -> barrier}; stage B(U+1)@P1, A(U+2)@P4; counted vmcnt(4)
// once per K-tile (never 0 mid-loop). T2 swizzle p = u ^ (row&7), linear
// gload dest + inverse-swizzled global source (rule #21).
// ---------------------------------------------------------------------------
__device__ __forceinline__ void rd_a8(const unsigned short* S, int base, int lrow, int lkg, short8 a[4][2]) {
    #pragma unroll
    for (int i = 0; i < 4; ++i)
        #pragma unroll
        for (int kk = 0; kk < 2; ++kk) {
            int row = base + i * 16 + lrow;
            int p = (kk * 4 + lkg) ^ (lrow & 7);
            a[i][kk] = *(const short8*)(S + row * 64 + p * 8);
        }
}
__device__ __forceinline__ void rd_b4(const unsigned short* S, int base, int lrow, int lkg, short8 b[2][2]) {
    #pragma unroll
    for (int j = 0; j < 2; ++j)
        #pragma unroll
        for (int kk = 0; kk < 2; ++kk) {
            int row = base + j * 16 + lrow;
            int p = (kk * 4 + lkg) ^ (lrow & 7);
            b[j][kk] = *(const short8*)(S + row * 64 + p * 8);
        }
}

__global__ __launch_bounds__(512) void gemm_bf16_8ph(const unsigned short* __restrict__ A, int lda,
                                                     const unsigned short* __restrict__ B, int ldb,
                                                     float* __restrict__ C, int ldc,
                                                     int K, const float* __restrict__ bias)
{
    __shared__ unsigned short As[2][256 * 64];
    __shared__ unsigned short Bs[2][256 * 64];
    const int tid = threadIdx.x;

    const int gm = gridDim.x;
    const int bid = blockIdx.y * gm + blockIdx.x;
    const int q = (gm * gridDim.y) >> 3;
    const int swz = (bid & 7) * q + (bid >> 3);
    const int bm = (swz % gm) * 256, bn = (swz / gm) * 256;

    const int wid = tid >> 6, lane = tid & 63;
    const int wr = wid >> 2, wc = wid & 3;          // 2 x 4 waves
    const int arow0 = wr * 128, brow0 = wc * 64;
    const int lrow = lane & 15, lkg = lane >> 4;

    // staging: thread t covers row sg = t>>3 (of a 64-row window), unit su = t&7.
    // slot (row, p) holds global k-unit p ^ (row & 7)  ->  source pre-swizzle.
    const int sg = tid >> 3, su = tid & 7;
    const int ksrc = (su ^ (sg & 7)) * 8;
    const unsigned short* Ag = A + (size_t)(bm + sg) * lda + ksrc;
    const unsigned short* Bg = B + (size_t)(bn + sg) * ldb + ksrc;

#define STG_A(buf, kt) do {                                                                                        \
    __builtin_amdgcn_global_load_lds(GPTR(Ag + (size_t)(kt) * 64),                       LPTR(&As[buf][tid * 8]), 16, 0, 0); \
    __builtin_amdgcn_global_load_lds(GPTR(Ag + (size_t)(kt) * 64 + (size_t)64 * lda),    LPTR(&As[buf][4096 + tid * 8]), 16, 0, 0); \
    __builtin_amdgcn_global_load_lds(GPTR(Ag + (size_t)(kt) * 64 + (size_t)128 * lda),   LPTR(&As[buf][8192 + tid * 8]), 16, 0, 0); \
    __builtin_amdgcn_global_load_lds(GPTR(Ag + (size_t)(kt) * 64 + (size_t)192 * lda),   LPTR(&As[buf][12288 + tid * 8]), 16, 0, 0); \
} while (0)
#define STG_B(buf, kt) do {                                                                                        \
    __builtin_amdgcn_global_load_lds(GPTR(Bg + (size_t)(kt) * 64),                       LPTR(&Bs[buf][tid * 8]), 16, 0, 0); \
    __builtin_amdgcn_global_load_lds(GPTR(Bg + (size_t)(kt) * 64 + (size_t)64 * ldb),    LPTR(&Bs[buf][4096 + tid * 8]), 16, 0, 0); \
    __builtin_amdgcn_global_load_lds(GPTR(Bg + (size_t)(kt) * 64 + (size_t)128 * ldb),   LPTR(&Bs[buf][8192 + tid * 8]), 16, 0, 0); \
    __builtin_amdgcn_global_load_lds(GPTR(Bg + (size_t)(kt) * 64 + (size_t)192 * ldb),   LPTR(&Bs[buf][12288 + tid * 8]), 16, 0, 0); \
} while (0)
#define MFMA_Q(IH, JH) do {                                                                                        \
    __builtin_amdgcn_s_setprio(1);                                                                                 \
    _Pragma("unroll") for (int i = 0; i < 4; ++i)                                                                  \
    _Pragma("unroll") for (int j = 0; j < 2; ++j)                                                                  \
    _Pragma("unroll") for (int kk = 0; kk < 2; ++kk)                                                               \
        acc[(IH) * 4 + i][(JH) * 2 + j] =                                                                          \
            __builtin_amdgcn_mfma_f32_16x16x32_bf16(a[i][kk], b[j][kk], acc[(IH) * 4 + i][(JH) * 2 + j], 0, 0, 0); \
    __builtin_amdgcn_s_setprio(0);                                                                                 \
} while (0)
#define PBAR() __builtin_amdgcn_s_barrier()

    f32x4 acc[8][4];
    #pragma unroll
    for (int i = 0; i < 8; ++i)
        #pragma unroll
        for (int j = 0; j < 4; ++j)
            acc[i][j] = f32x4{0.f, 0.f, 0.f, 0.f};

    short8 a[4][2], b[2][2];
    const int NT = K >> 6;

    // prologue: tile0 -> buf0 (A+B), tile1 A -> buf1; wait tile0 landed.
    STG_A(0, 0); STG_B(0, 0); STG_A(1, 1);
    asm volatile("s_waitcnt vmcnt(4)" ::: "memory");
    PBAR();

    int buf = 0;
    for (int U = 0; U < NT; ++U, buf ^= 1) {
        // P1: stage B(U+1) -> other buf; read A(ih=0), B(jh=0); MFMA Q(0,0)
        if (U + 1 < NT) STG_B(buf ^ 1, U + 1);
        rd_a8(As[buf], arow0, lrow, lkg, a);
        rd_b4(Bs[buf], brow0, lrow, lkg, b);
        PBAR(); __builtin_amdgcn_sched_barrier(0);
        MFMA_Q(0, 0);
        PBAR();
        // P2: read B(jh=1); MFMA Q(0,1)  [A kept in regs]
        rd_b4(Bs[buf], brow0 + 32, lrow, lkg, b);
        PBAR(); __builtin_amdgcn_sched_barrier(0);
        MFMA_Q(0, 1);
        PBAR();
        // P3: read A(ih=1); MFMA Q(1,1)  [B kept]
        rd_a8(As[buf], arow0 + 64, lrow, lkg, a);
        PBAR(); __builtin_amdgcn_sched_barrier(0);
        MFMA_Q(1, 1);
        PBAR();
        // P4: read B(jh=0); stage A(U+2) -> this buf (A last read in P3);
        //     counted vmcnt(4): everything older than A(U+2) has landed.
        rd_b4(Bs[buf], brow0, lrow, lkg, b);
        if (U + 2 < NT) {
            STG_A(buf, U + 2);
            asm volatile("s_waitcnt vmcnt(4)" ::: "memory");
        } else {
            asm volatile("s_waitcnt vmcnt(0)" ::: "memory");
        }
        PBAR(); __builtin_amdgcn_sched_barrier(0);
        MFMA_Q(1, 0);
        PBAR();
    }
#undef STG_A
#undef STG_B
#undef MFMA_Q
#undef PBAR

    const int crow = bm + arow0 + lkg * 4;
    const int ccol = bn + brow0 + lrow;
    #pragma unroll
    for (int i = 0; i < 8; ++i) {
        #pragma unroll
        for (int j = 0; j < 4; ++j) {
            float bv = bias[ccol + 16 * j];
            float* Cp = C + (size_t)(crow + 16 * i) * ldc + ccol + 16 * j;
            #pragma unroll
            for (int r = 0; r < 4; ++r)
                Cp[(size_t)r * ldc] = acc[i][j][r] + bv;
        }
    }
}

// ---------------------------------------------------------------------------
// Reduce XSK split-K partials -> xdbl (fp32) + xdbl_b (bf16)
// ---------------------------------------------------------------------------
__global__ __launch_bounds__(256) void reduce_xdbl(const float* __restrict__ part,
                                                   float* __restrict__ xdbl,
                                                   unsigned short* __restrict__ xdbl_b)
{
    int i = blockIdx.x * 256 + threadIdx.x;     // over 2048*128/4 = 65536
    float4 s = ((const float4*)part)[i];
    #pragma unroll
    for (int z = 1; z < XSK; ++z) {
        float4 v = ((const float4*)part)[(size_t)z * (M_ROWS * XPAD / 4) + i];
        s.x += v.x; s.y += v.y; s.z += v.z; s.w += v.w;
    }
    ((float4*)xdbl)[i] = s;
    ushort4 o;
    o.x = f2bf(s.x); o.y = f2bf(s.y); o.z = f2bf(s.z); o.w = f2bf(s.w);
    ((ushort4*)xdbl_b)[i] = o;
}

// ---------------------------------------------------------------------------
// Causal depthwise conv1d (k=4) + bias + SiLU; bf16 in (xzb) -> bf16 out (xcb)
// ---------------------------------------------------------------------------
__global__ __launch_bounds__(256) void conv_silu_kernel(const unsigned short* __restrict__ xzb,
                                                        const float* __restrict__ cw,
                                                        const float* __restrict__ cb,
                                                        unsigned short* __restrict__ xcb)
{
    int idx = blockIdx.x * 256 + threadIdx.x;
    int d = idx & (D_INNER - 1);
    int m = idx >> 11;
    int l = m & (SEQ - 1);
    int b = m >> 10;
    float w0 = cw[d * 4 + 0], w1 = cw[d * 4 + 1], w2 = cw[d * 4 + 2], w3 = cw[d * 4 + 3];
    float s = cb[d];
    const unsigned short* base = xzb + ((size_t)b * SEQ) * (2 * D_INNER) + d;
    if (l - 3 >= 0) s += bf2f(base[(size_t)(l - 3) * (2 * D_INNER)]) * w0;
    if (l - 2 >= 0) s += bf2f(base[(size_t)(l - 2) * (2 * D_INNER)]) * w1;
    if (l - 1 >= 0) s += bf2f(base[(size_t)(l - 1) * (2 * D_INNER)]) * w2;
    s += bf2f(base[(size_t)l * (2 * D_INNER)]) * w3;
    float v = s * sigmoidf_(s);
    xcb[(size_t)m * D_INNER + d] = f2bf(v);
}

// ---------------------------------------------------------------------------
// Chunk-parallel selective scan (linear recurrence decomposition).
// ---------------------------------------------------------------------------
__global__ __launch_bounds__(256) void scan_partial(const unsigned short* __restrict__ dtb,
                                                    const float* __restrict__ xdbl,
                                                    const unsigned short* __restrict__ xcb,
                                                    const float* __restrict__ A_log,
                                                    float* __restrict__ H,
                                                    float* __restrict__ P)
{
    const int tid = threadIdx.x;
    const int b = blockIdx.x & 1;
    const int c = (blockIdx.x >> 1) & (NC - 1);
    const int d = ((blockIdx.x >> 6) << 8) + tid;

    __shared__ float Bsm[LC][8];
    {
        int r = tid >> 3, n = tid & 7;
        Bsm[r][n] = xdbl[(size_t)(b * SEQ + c * LC + r) * XPAD + DT_RANK + n];
    }
    __syncthreads();

    float An[8];
    #pragma unroll
    for (int n = 0; n < 8; ++n) An[n] = -__expf(A_log[d * 8 + n]);
    float h[8] = {0.f,0.f,0.f,0.f,0.f,0.f,0.f,0.f};
    float p[8] = {1.f,1.f,1.f,1.f,1.f,1.f,1.f,1.f};

    const unsigned short* dtp = dtb + (size_t)(b * SEQ + c * LC) * D_INNER + d;
    const unsigned short* xcp = xcb + (size_t)(b * SEQ + c * LC) * D_INNER + d;
    for (int l = 0; l < LC; ++l) {
        float dtv = bf2f(dtp[(size_t)l * D_INNER]);
        float ux  = dtv * bf2f(xcp[(size_t)l * D_INNER]);
        #pragma unroll
        for (int n = 0; n < 8; ++n) {
            float dA = __expf(dtv * An[n]);
            h[n] = dA * h[n] + Bsm[l][n] * ux;
            p[n] *= dA;
        }
    }
    size_t base = (size_t)((b * NC + c) * 8) * D_INNER + d;
    #pragma unroll
    for (int n = 0; n < 8; ++n) {
        H[base + (size_t)n * D_INNER] = h[n];
        P[base + (size_t)n * D_INNER] = p[n];
    }
}

__global__ __launch_bounds__(256) void scan_combine(const float* __restrict__ H,
                                                    float* __restrict__ P /* -> h0 */)
{
    int idx = blockIdx.x * 256 + threadIdx.x;   // 32768 = 2*8*2048
    int d = idx & (D_INNER - 1);
    int n = (idx >> 11) & 7;
    int b = idx >> 14;
    float hp = 0.f;
    for (int c = 0; c < NC; ++c) {
        size_t base = (size_t)((b * NC + c) * 8 + n) * D_INNER + d;
        float Pv = P[base], Hv = H[base];
        P[base] = hp;
        hp = Pv * hp + Hv;
    }
}

__global__ __launch_bounds__(256) void scan_final(const unsigned short* __restrict__ dtb,
                                                  const float* __restrict__ xdbl,
                                                  const unsigned short* __restrict__ xcb,
                                                  const unsigned short* __restrict__ xzb,
                                                  const float* __restrict__ A_log,
                                                  const float* __restrict__ Dp,
                                                  const float* __restrict__ h0,
                                                  unsigned short* __restrict__ yb)
{
    const int tid = threadIdx.x;
    const int b = blockIdx.x & 1;
    const int c = (blockIdx.x >> 1) & (NC - 1);
    const int d = ((blockIdx.x >> 6) << 8) + tid;

    __shared__ float Bsm[LC][8];
    __shared__ float Csm[LC][8];
    {
        int r = tid >> 3, n = tid & 7;
        size_t xrow = (size_t)(b * SEQ + c * LC + r) * XPAD;
        Bsm[r][n] = xdbl[xrow + DT_RANK + n];
        Csm[r][n] = xdbl[xrow + DT_RANK + 8 + n];
    }
    __syncthreads();

    float An[8], h[8];
    size_t base = (size_t)((b * NC + c) * 8) * D_INNER + d;
    #pragma unroll
    for (int n = 0; n < 8; ++n) {
        An[n] = -__expf(A_log[d * 8 + n]);
        h[n] = h0[base + (size_t)n * D_INNER];
    }
    const float Dv = Dp[d];

    const unsigned short* dtp = dtb + (size_t)(b * SEQ + c * LC) * D_INNER + d;
    const unsigned short* xcp = xcb + (size_t)(b * SEQ + c * LC) * D_INNER + d;
    const unsigned short* zp  = xzb + (size_t)(b * SEQ + c * LC) * (2 * D_INNER) + D_INNER + d;
    unsigned short* ybp = yb + (size_t)(b * SEQ + c * LC) * D_INNER + d;

    for (int l = 0; l < LC; ++l) {
        float dtv = bf2f(dtp[(size_t)l * D_INNER]);
        float xcv = bf2f(xcp[(size_t)l * D_INNER]);
        float zv  = bf2f(zp[(size_t)l * (2 * D_INNER)]);
        float ux = dtv * xcv;
        float acc = 0.f;
        #pragma unroll
        for (int n = 0; n < 8; ++n) {
            float dA = __expf(dtv * An[n]);
            h[n] = dA * h[n] + Bsm[l][n] * ux;
            acc += h[n] * Csm[l][n];
        }
        float yv = (acc + xcv * Dv) * (zv * sigmoidf_(zv));
        ybp[(size_t)l * D_INNER] = f2bf(yv);
    }
}

// ---------------------------------------------------------------------------
// LayerNorm (1024). ADD: out = LN(extra + xin) else LN(xin). Emits fp32 + bf16.
// ---------------------------------------------------------------------------
template<bool ADD>
__global__ __launch_bounds__(256) void ln_kernel(const float* __restrict__ extra,
                                                 const float* __restrict__ xin,
                                                 float* __restrict__ xout,
                                                 unsigned short* __restrict__ xbout,
                                                 const float* __restrict__ g,
                                                 const float* __restrict__ bb)
{
    int m = blockIdx.x;
    int t = threadIdx.x;
    float4 v = ((const float4*)(xin + (size_t)m * D_MODEL))[t];
    if (ADD) {
        float4 e = ((const float4*)(extra + (size_t)m * D_MODEL))[t];
        v.x += e.x; v.y += e.y; v.z += e.z; v.w += e.w;
    }
    float s  = v.x + v.y + v.z + v.w;
    float s2 = v.x * v.x + v.y * v.y + v.z * v.z + v.w * v.w;
    for (int off = 32; off; off >>= 1) {
        s  += __shfl_down(s, off);
        s2 += __shfl_down(s2, off);
    }
    __shared__ float red[8];
    int wid = t >> 6, lane = t & 63;
    if (lane == 0) { red[wid] = s; red[wid + 4] = s2; }
    __syncthreads();
    if (t == 0) {
        float a  = red[0] + red[1] + red[2] + red[3];
        float b2 = red[4] + red[5] + red[6] + red[7];
        float mu = a * (1.f / D_MODEL);
        red[0] = mu;
        red[4] = b2 * (1.f / D_MODEL) - mu * mu;
    }
    __syncthreads();
    float mu = red[0];
    float rs = rsqrtf(red[4] + 1e-5f);
    float4 gg = ((const float4*)g)[t];
    float4 bv = ((const float4*)bb)[t];
    float4 o;
    o.x = (v.x - mu) * rs * gg.x + bv.x;
    o.y = (v.y - mu) * rs * gg.y + bv.y;
    o.z = (v.z - mu) * rs * gg.z + bv.z;
    o.w = (v.w - mu) * rs * gg.w + bv.w;
    ((float4*)(xout + (size_t)m * D_MODEL))[t] = o;
    ushort4 ob;
    ob.x = f2bf(o.x); ob.y = f2bf(o.y); ob.z = f2bf(o.z); ob.w = f2bf(o.w);
    ((ushort4*)(xbout + (size_t)m * D_MODEL))[t] = ob;
}

// ---------------------------------------------------------------------------
extern "C" void kernel_launch(void* const* d_in, const int* in_sizes, int n_in,
                              void* d_out, int out_size, void* d_ws, size_t ws_size,
                              hipStream_t stream)
{
    const int*   ids      = (const int*)d_in[0];
    const float* embed    = (const float*)d_in[1];
    const float* in_proj  = (const float*)d_in[2];
    const float* conv_w   = (const float*)d_in[3];
    const float* conv_b   = (const float*)d_in[4];
    const float* x_proj   = (const float*)d_in[5];
    const float* dt_w     = (const float*)d_in[6];
    const float* dt_b     = (const float*)d_in[7];
    const float* A_log    = (const float*)d_in[8];
    const float* Dp       = (const float*)d_in[9];
    const float* out_proj = (const float*)d_in[10];
    const float* ln_g     = (const float*)d_in[11];
    const float* ln_b     = (const float*)d_in[12];
    const float* fn_g     = (const float*)d_in[13];
    const float* fn_b     = (const float*)d_in[14];
    const float* fc_w     = (const float*)d_in[15];
    const float* fc_b     = (const float*)d_in[16];
    float* logits = (float*)d_out;

    // ---- workspace layout (fp32 first, then bf16) ----
    float* ws = (float*)d_ws;
    float* x     = ws;                                   // 2048*1024
    float* xdbl  = x + (size_t)M_ROWS * D_MODEL;         // 2048*128
    float* tmp   = xdbl + (size_t)M_ROWS * XPAD;         // 2048*1024 (H/P alias)
    float* xpart = tmp + (size_t)M_ROWS * D_MODEL;       // XSK*2048*128

    float* Hbuf = tmp;
    float* Pbuf = tmp + (size_t)BATCH * NC * D_STATE * D_INNER;

    unsigned short* xb     = (unsigned short*)(xpart + (size_t)XSK * M_ROWS * XPAD);
    unsigned short* yb     = xb + (size_t)M_ROWS * D_MODEL;
    unsigned short* xzb    = yb + (size_t)M_ROWS * D_INNER;
    unsigned short* xcb    = xzb + (size_t)M_ROWS * 2 * D_INNER;
    unsigned short* dtb    = xcb + (size_t)M_ROWS * D_INNER;
    unsigned short* xdbl_b = dtb + (size_t)M_ROWS * D_INNER;
    unsigned short* wb_in  = xdbl_b + (size_t)M_ROWS * XPAD;
    unsigned short* wb_out = wb_in + (size_t)NLAYERS * 2 * D_INNER * D_MODEL;
    unsigned short* wb_fc  = wb_out + (size_t)NLAYERS * D_MODEL * D_INNER;
    unsigned short* wb_x   = wb_fc + (size_t)VOCAB * D_MODEL;
    unsigned short* wb_dt  = wb_x + (size_t)NLAYERS * XPAD * D_INNER;

    // ---- weight casts ----
    {
        int n4 = NLAYERS * 2 * D_INNER * D_MODEL / 4;
        cast_kernel<<<(n4 + 255) / 256, 256, 0, stream>>>(in_proj, wb_in, n4);
        n4 = NLAYERS * D_MODEL * D_INNER / 4;
        cast_kernel<<<(n4 + 255) / 256, 256, 0, stream>>>(out_proj, wb_out, n4);
        n4 = VOCAB * D_MODEL / 4;
        cast_kernel<<<(n4 + 255) / 256, 256, 0, stream>>>(fc_w, wb_fc, n4);
        n4 = NLAYERS * D_INNER * DT_RANK / 4;
        cast_kernel<<<(n4 + 255) / 256, 256, 0, stream>>>(dt_w, wb_dt, n4);
        n4 = NLAYERS * XPAD * D_INNER / 4;
        cast_pad_xproj<<<(n4 + 255) / 256, 256, 0, stream>>>(x_proj, wb_x);
    }

    // ---- embedding (fp32 + bf16) ----
    gather_kernel<<<M_ROWS, 256, 0, stream>>>(ids, embed, x, xb);

    for (int i = 0; i < NLAYERS; ++i) {
        const unsigned short* W_in_b  = wb_in + (size_t)i * 2 * D_INNER * D_MODEL;
        const unsigned short* W_out_b = wb_out + (size_t)i * D_MODEL * D_INNER;
        const unsigned short* W_x_b   = wb_x + (size_t)i * XPAD * D_INNER;
        const unsigned short* W_dt_b  = wb_dt + (size_t)i * D_INNER * DT_RANK;
        const float* cw    = conv_w + (size_t)i * D_INNER * 4;
        const float* cb    = conv_b + (size_t)i * D_INNER;
        const float* b_dt  = dt_b + (size_t)i * D_INNER;
        const float* Al    = A_log + (size_t)i * D_INNER * D_STATE;
        const float* Dl    = Dp + (size_t)i * D_INNER;
        const float* g     = ln_g + (size_t)i * D_MODEL;
        const float* bb    = ln_b + (size_t)i * D_MODEL;

        // xz(bf16) = x @ in_proj^T   (2048 x 4096, K=1024)   grid 16x32
        gemm_bf16_nt<1><<<dim3(M_ROWS / 128, 2 * D_INNER / 128), 256, 0, stream>>>(
            xb, D_MODEL, W_in_b, D_MODEL, xzb, 2 * D_INNER, D_MODEL, nullptr);

        // xc(bf16) = silu(conv(xz[:, :2048]) + cb)
        conv_silu_kernel<<<(M_ROWS * D_INNER) / 256, 256, 0, stream>>>(xzb, cw, cb, xcb);

        // x_dbl partials: (2048 x 128, K=2048 split XSK x 256)  grid 16x1x8
        gemm_bf16_nt<0><<<dim3(M_ROWS / 128, 1, XSK), 256, 0, stream>>>(
            xcb, D_INNER, W_x_b, D_INNER, xpart, XPAD, D_INNER / XSK, nullptr);
        reduce_xdbl<<<(M_ROWS * XPAD / 4) / 256, 256, 0, stream>>>(xpart, xdbl, xdbl_b);

        // dt(bf16) = softplus(x_dbl[:, :64] @ dt_w^T + b_dt)  (2048x2048, K=64) grid 16x16
        gemm_bf16_nt<3><<<dim3(M_ROWS / 128, D_INNER / 128), 256, 0, stream>>>(
            xdbl_b, XPAD, W_dt_b, DT_RANK, dtb, D_INNER, DT_RANK, b_dt);

        // chunk-parallel scan -> yb (bf16)
        scan_partial<<<BATCH * NC * (D_INNER / 256), 256, 0, stream>>>(
            dtb, xdbl, xcb, Al, Hbuf, Pbuf);
        scan_combine<<<(BATCH * D_STATE * D_INNER) / 256, 256, 0, stream>>>(Hbuf, Pbuf);
        scan_final<<<BATCH * NC * (D_INNER / 256), 256, 0, stream>>>(
            dtb, xdbl, xcb, xzb, Al, Dl, Pbuf, yb);

        // tmp(fp32) = y @ out_proj^T   (2048 x 1024, K=2048)   grid 16x8
        gemm_bf16_nt<0><<<dim3(M_ROWS / 128, D_MODEL / 128), 256, 0, stream>>>(
            yb, D_INNER, W_out_b, D_INNER, tmp, D_MODEL, D_INNER, nullptr);

        // x = LN(tmp + x)  (fp32 + bf16)
        ln_kernel<true><<<M_ROWS, 256, 0, stream>>>(tmp, x, x, xb, g, bb);
    }

    // final LN -> tmp + xb
    ln_kernel<false><<<M_ROWS, 256, 0, stream>>>(nullptr, x, tmp, xb, fn_g, fn_b);

    // logits = xf @ fc_w^T + fc_b   (2048 x 32000, K=1024)  8-phase 256² grid 8x125
    gemm_bf16_8ph<<<dim3(M_ROWS / 256, VOCAB / 256), 512, 0, stream>>>(
        xb, D_MODEL, wb_fc, D_MODEL, logits, VOCAB, D_MODEL, fc_b);
}

// Round 10
// 899.109 us; speedup vs baseline: 1.1229x; 1.1147x over previous
//
#include <hip/hip_runtime.h>
#include <cstddef>
#include <cstdint>

#define D_MODEL 1024
#define D_INNER 2048
#define DT_RANK 64
#define D_STATE 8
#define NLAYERS 4
#define BATCH 2
#define SEQ 1024
#define M_ROWS (BATCH*SEQ)   /* 2048 */
#define VOCAB 32000
#define XPAD 128             /* x_proj N padded 80 -> 128 */
#define NC 32                /* scan chunks */
#define LC 32                /* chunk length (NC*LC == SEQ) */
#define XSK 16               /* x_proj split-K factor */
#define OSK 2                /* out_proj split-K factor */

typedef __attribute__((ext_vector_type(8))) short short8;
typedef __attribute__((ext_vector_type(4))) float f32x4;

#define GPTR(p) (const __attribute__((address_space(1))) void*)(p)
#define LPTR(p) (__attribute__((address_space(3))) void*)(p)

__device__ __forceinline__ float sigmoidf_(float x) { return 1.f / (1.f + __expf(-x)); }

__device__ __forceinline__ unsigned short f2bf(float f) {
    unsigned u = __float_as_uint(f);
    u += 0x7fffu + ((u >> 16) & 1u);         // round-to-nearest-even
    return (unsigned short)(u >> 16);
}
__device__ __forceinline__ float bf2f(unsigned short u) {
    return __uint_as_float((unsigned)u << 16);
}

// ---------------------------------------------------------------------------
// fp32 -> bf16 cast (contiguous), 4 elems/thread.
// ---------------------------------------------------------------------------
__global__ __launch_bounds__(256) void cast_kernel(const float* __restrict__ in,
                                                   unsigned short* __restrict__ out, int n4)
{
    int i = blockIdx.x * 256 + threadIdx.x;
    if (i >= n4) return;
    float4 v = ((const float4*)in)[i];
    ushort4 o;
    o.x = f2bf(v.x); o.y = f2bf(v.y); o.z = f2bf(v.z); o.w = f2bf(v.w);
    ((ushort4*)out)[i] = o;
}

// ---------------------------------------------------------------------------
// x_proj weight: cast 4x(80,2048) fp32 -> 4x(128,2048) bf16, rows 80..127 = 0
// ---------------------------------------------------------------------------
__global__ __launch_bounds__(256) void cast_pad_xproj(const float* __restrict__ in,
                                                      unsigned short* __restrict__ out)
{
    int i = blockIdx.x * 256 + threadIdx.x;     // over 4*128*2048/4 = 262144
    if (i >= NLAYERS * XPAD * D_INNER / 4) return;
    int col4 = i & (D_INNER / 4 - 1);           // 512 col-groups
    int row = (i >> 9) & (XPAD - 1);
    int layer = i >> 16;
    ushort4 o = {0, 0, 0, 0};
    if (row < 80) {
        float4 v = ((const float4*)(in + ((size_t)layer * 80 + row) * D_INNER))[col4];
        o.x = f2bf(v.x); o.y = f2bf(v.y); o.z = f2bf(v.z); o.w = f2bf(v.w);
    }
    ((ushort4*)out)[i] = o;
}

// ---------------------------------------------------------------------------
// Embedding gather -> x (fp32) and xb (bf16)
// ---------------------------------------------------------------------------
__global__ __launch_bounds__(256) void gather_kernel(const int* __restrict__ ids,
                                                     const float* __restrict__ embed,
                                                     float* __restrict__ x,
                                                     unsigned short* __restrict__ xb)
{
    int m = blockIdx.x;
    int t = threadIdx.x;
    int id = ids[m];
    float4 v = ((const float4*)(embed + (size_t)id * D_MODEL))[t];
    ((float4*)(x + (size_t)m * D_MODEL))[t] = v;
    ushort4 o;
    o.x = f2bf(v.x); o.y = f2bf(v.y); o.z = f2bf(v.z); o.w = f2bf(v.w);
    ((ushort4*)(xb + (size_t)m * D_MODEL))[t] = o;
}

// ---------------------------------------------------------------------------
// bf16 MFMA GEMM  C[M,N] = A[M,K] * B[N,K]^T
// 128x128 tile, BK=32, 4 waves. Double-buffered LDS, counted-vmcnt pipeline.
// EPI: 0 fp32 (+splitK z-offset) | 1 bf16 | 2 fp32 +bias | 3 bf16 softplus(v+bias)
// ---------------------------------------------------------------------------
template<int EPI>
__global__ __launch_bounds__(256) void gemm_bf16_nt(const unsigned short* __restrict__ A, int lda,
                                                    const unsigned short* __restrict__ B, int ldb,
                                                    void* __restrict__ Cv, int ldc,
                                                    int K, const float* __restrict__ bias)
{
    __shared__ unsigned short As[2][128 * 32];
    __shared__ unsigned short Bs[2][128 * 32];
    const int tid = threadIdx.x;

    const int gm = gridDim.x;
    const int bid = blockIdx.y * gm + blockIdx.x;
    const int q = (gm * gridDim.y) >> 3;           // nwg % 8 == 0 guaranteed
    const int swz = (bid & 7) * q + (bid >> 3);
    const int bm = (swz % gm) * 128, bn = (swz / gm) * 128;

    const int wid = tid >> 6, lane = tid & 63;
    const int wm = (wid >> 1) * 64, wn = (wid & 1) * 64;
    const int lrow = lane & 15, lkg = lane >> 4;

    const int srow = tid >> 2;                               // 0..63
    const int ksrc = ((tid & 3) ^ ((srow >> 1) & 3)) * 8;    // elems, const/thread
    const size_t kz = (size_t)blockIdx.z * K;
    const unsigned short* Ag = A + (size_t)(bm + srow) * lda + kz + ksrc;
    const unsigned short* Bg = B + (size_t)(bn + srow) * ldb + kz + ksrc;
    const size_t r64a = (size_t)64 * lda;
    const size_t r64b = (size_t)64 * ldb;

#define STAGE(buf, koff)                                                                              \
    do {                                                                                              \
        __builtin_amdgcn_global_load_lds(GPTR(Ag + (koff)),        LPTR(&As[buf][tid * 8]), 16, 0, 0);\
        __builtin_amdgcn_global_load_lds(GPTR(Ag + r64a + (koff)), LPTR(&As[buf][2048 + tid * 8]), 16, 0, 0);\
        __builtin_amdgcn_global_load_lds(GPTR(Bg + (koff)),        LPTR(&Bs[buf][tid * 8]), 16, 0, 0);\
        __builtin_amdgcn_global_load_lds(GPTR(Bg + r64b + (koff)), LPTR(&Bs[buf][2048 + tid * 8]), 16, 0, 0);\
    } while (0)

    f32x4 acc[4][4];
    #pragma unroll
    for (int i = 0; i < 4; ++i)
        #pragma unroll
        for (int j = 0; j < 4; ++j)
            acc[i][j] = f32x4{0.f, 0.f, 0.f, 0.f};

    STAGE(0, 0);                      // prologue

    int cur = 0;
    for (int k0 = 0; k0 < K; k0 += 32) {
        if (k0 + 32 < K) {
            STAGE(cur ^ 1, k0 + 32);                             // next tile in flight
            asm volatile("s_waitcnt vmcnt(4)" ::: "memory");     // cur's 4 landed
        } else {
            asm volatile("s_waitcnt vmcnt(0)" ::: "memory");     // final drain
        }
        __builtin_amdgcn_s_barrier();          // publish cur to all waves
        __builtin_amdgcn_sched_barrier(0);     // pin: no hoisting above the wait

        short8 af[4], bf[4];
        #pragma unroll
        for (int i = 0; i < 4; ++i) {
            int ra = wm + 16 * i + lrow;
            int pa = lkg ^ ((ra >> 1) & 3);
            af[i] = *(const short8*)(&As[cur][ra * 32 + pa * 8]);
            int rb = wn + 16 * i + lrow;
            int pb = lkg ^ ((rb >> 1) & 3);
            bf[i] = *(const short8*)(&Bs[cur][rb * 32 + pb * 8]);
        }
        __builtin_amdgcn_s_setprio(1);
        #pragma unroll
        for (int i = 0; i < 4; ++i)
            #pragma unroll
            for (int j = 0; j < 4; ++j)
                acc[i][j] = __builtin_amdgcn_mfma_f32_16x16x32_bf16(af[i], bf[j], acc[i][j], 0, 0, 0);
        __builtin_amdgcn_s_setprio(0);

        __builtin_amdgcn_s_barrier();          // all reads of cur done before overwrite
        cur ^= 1;
    }
#undef STAGE

    const int crow = bm + wm + lkg * 4;
    const int ccol = bn + wn + lrow;
    #pragma unroll
    for (int i = 0; i < 4; ++i) {
        #pragma unroll
        for (int j = 0; j < 4; ++j) {
            float bv = (EPI == 2 || EPI == 3) ? bias[ccol + 16 * j] : 0.f;
            #pragma unroll
            for (int r = 0; r < 4; ++r) {
                float v = acc[i][j][r] + bv;
                size_t off = (size_t)(crow + 16 * i + r) * ldc + ccol + 16 * j;
                if (EPI == 0) {
                    ((float*)Cv)[(size_t)blockIdx.z * M_ROWS * ldc + off] = v;
                } else if (EPI == 2) {
                    ((float*)Cv)[off] = v;
                } else {
                    if (EPI == 3) v = (v > 20.f) ? v : log1pf(__expf(v));
                    ((unsigned short*)Cv)[off] = f2bf(v);
                }
            }
        }
    }
}

// ---------------------------------------------------------------------------
// 8-phase 256x256 GEMM, m201 template with ONE HALF-TILE STAGED PER PHASE
// (m196 fine-interleave) and per-phase counted vmcnt(4).
// 512 thr = 8 waves (2M x 4N); 2 K-tiles (BK=64) per iteration; LDS 128 KiB.
// Stage schedule (iter i, T0=2i->dbuf0, T1=2i+1->dbuf1):
//   P1:A(T1)h1  P2:B(T1)h0  P3:B(T1)h1  P4:A(T0+2)h0  P5:A(T0+2)h1
//   P6:B(T0+2)h0  P7:B(T0+2)h1  P8:A(T1+2)h0
// Every stage->first-read distance >= 3 phases => vmcnt(4) (last 2 phases
// pending) at each phase guarantees phase p+1's ds_reads. Wave wc's B rows:
// b0 = wc*32 (half0), b1 = 128+wc*32 (half1) so halves free on schedule.
// ---------------------------------------------------------------------------
__device__ __forceinline__ void rd_a8(const unsigned short* S, int base, int lrow, int lkg, short8 a[4][2]) {
    #pragma unroll
    for (int i = 0; i < 4; ++i)
        #pragma unroll
        for (int kk = 0; kk < 2; ++kk) {
            int row = base + i * 16 + lrow;
            int p = (kk * 4 + lkg) ^ (lrow & 7);
            a[i][kk] = *(const short8*)(S + row * 64 + p * 8);
        }
}
__device__ __forceinline__ void rd_b4(const unsigned short* S, int base, int lrow, int lkg, short8 b[2][2]) {
    #pragma unroll
    for (int j = 0; j < 2; ++j)
        #pragma unroll
        for (int kk = 0; kk < 2; ++kk) {
            int row = base + j * 16 + lrow;
            int p = (kk * 4 + lkg) ^ (lrow & 7);
            b[j][kk] = *(const short8*)(S + row * 64 + p * 8);
        }
}

__global__ __launch_bounds__(512) void gemm_bf16_8ph(const unsigned short* __restrict__ A, int lda,
                                                     const unsigned short* __restrict__ B, int ldb,
                                                     float* __restrict__ C, int ldc,
                                                     int K, const float* __restrict__ bias)
{
    __shared__ unsigned short As[2][256 * 64];
    __shared__ unsigned short Bs[2][256 * 64];
    const int tid = threadIdx.x;

    const int gm = gridDim.x;
    const int bid = blockIdx.y * gm + blockIdx.x;
    const int q = (gm * gridDim.y) >> 3;
    const int swz = (bid & 7) * q + (bid >> 3);
    const int bm = (swz % gm) * 256, bn = (swz / gm) * 256;

    const int wid = tid >> 6, lane = tid & 63;
    const int wr = wid >> 2, wc = wid & 3;
    const int arow0 = wr * 128;                 // wave's A half
    const int b0r = wc * 32, b1r = 128 + wc * 32;
    const int lrow = lane & 15, lkg = lane >> 4;

    const int sg = tid >> 3, su = tid & 7;      // staging row-in-64 / unit
    const int ksrc = (su ^ (sg & 7)) * 8;       // inverse-swizzled global src
    const unsigned short* Ag = A + (size_t)(bm + sg) * lda + ksrc;
    const unsigned short* Bg = B + (size_t)(bn + sg) * ldb + ksrc;

#define STG_A_H(buf, kt, h) do {                                                                   \
    __builtin_amdgcn_global_load_lds(GPTR(Ag + (size_t)(kt) * 64 + (size_t)((h) * 128) * lda),     \
                                     LPTR(&As[buf][(h) * 8192 + tid * 8]), 16, 0, 0);              \
    __builtin_amdgcn_global_load_lds(GPTR(Ag + (size_t)(kt) * 64 + (size_t)((h) * 128 + 64) * lda),\
                                     LPTR(&As[buf][(h) * 8192 + 4096 + tid * 8]), 16, 0, 0);       \
} while (0)
#define STG_B_H(buf, kt, h) do {                                                                   \
    __builtin_amdgcn_global_load_lds(GPTR(Bg + (size_t)(kt) * 64 + (size_t)((h) * 128) * ldb),     \
                                     LPTR(&Bs[buf][(h) * 8192 + tid * 8]), 16, 0, 0);              \
    __builtin_amdgcn_global_load_lds(GPTR(Bg + (size_t)(kt) * 64 + (size_t)((h) * 128 + 64) * ldb),\
                                     LPTR(&Bs[buf][(h) * 8192 + 4096 + tid * 8]), 16, 0, 0);       \
} while (0)
#define WAIT4() asm volatile("s_waitcnt vmcnt(4)" ::: "memory")
#define WAIT0() asm volatile("s_waitcnt vmcnt(0)" ::: "memory")
#define PBAR() __builtin_amdgcn_s_barrier()
#define SBAR() __builtin_amdgcn_sched_barrier(0)
#define MFMA_Q(QA, BH) do {                                                                        \
    __builtin_amdgcn_s_setprio(1);                                                                 \
    _Pragma("unroll") for (int i = 0; i < 4; ++i)                                                  \
    _Pragma("unroll") for (int j = 0; j < 2; ++j)                                                  \
    _Pragma("unroll") for (int kk = 0; kk < 2; ++kk)                                               \
        acc[(QA) * 4 + i][(BH) * 2 + j] =                                                          \
            __builtin_amdgcn_mfma_f32_16x16x32_bf16(a[i][kk], b[j][kk],                            \
                                                    acc[(QA) * 4 + i][(BH) * 2 + j], 0, 0, 0);     \
    __builtin_amdgcn_s_setprio(0);                                                                 \
} while (0)

    f32x4 acc[8][4];
    #pragma unroll
    for (int i = 0; i < 8; ++i)
        #pragma unroll
        for (int j = 0; j < 4; ++j)
            acc[i][j] = f32x4{0.f, 0.f, 0.f, 0.f};

    short8 a[4][2], b[2][2];
    const int NT = K >> 6;        // 16 K-tiles
    const int NI = NT >> 1;       // 8 iterations

    // prologue: tile0 (4 halves) + A(1)h0; drain to tile0-landed.
    STG_A_H(0, 0, 0); STG_A_H(0, 0, 1); STG_B_H(0, 0, 0); STG_B_H(0, 0, 1);
    STG_A_H(1, 1, 0);
    asm volatile("s_waitcnt vmcnt(2)" ::: "memory");
    PBAR();

    for (int it = 0; it < NI; ++it) {
        const int T0 = 2 * it, T1 = 2 * it + 1;
        const bool more = (it + 1 < NI);

        // P1: stage A(T1)h1; read a0(T0), b0(T0); Q(0,0)
        STG_A_H(1, T1, 1);
        rd_a8(As[0], arow0, lrow, lkg, a);
        rd_b4(Bs[0], b0r, lrow, lkg, b);
        WAIT4(); PBAR(); SBAR();
        MFMA_Q(0, 0);
        PBAR();
        // P2: stage B(T1)h0; read b1(T0); Q(0,1)
        STG_B_H(1, T1, 0);
        rd_b4(Bs[0], b1r, lrow, lkg, b);
        WAIT4(); PBAR(); SBAR();
        MFMA_Q(0, 1);
        PBAR();
        // P3: stage B(T1)h1; read a1(T0); Q(1,1)
        STG_B_H(1, T1, 1);
        rd_a8(As[0], arow0 + 64, lrow, lkg, a);
        WAIT4(); PBAR(); SBAR();
        MFMA_Q(1, 1);
        PBAR();
        // P4: stage A(T0+2)h0; re-read b0(T0); Q(1,0)
        rd_b4(Bs[0], b0r, lrow, lkg, b);
        if (more) { STG_A_H(0, T0 + 2, 0); WAIT4(); } else { WAIT0(); }
        PBAR(); SBAR();
        MFMA_Q(1, 0);
        PBAR();
        // P5: stage A(T0+2)h1; read a0(T1), b0(T1); Q(0,0)
        if (more) STG_A_H(0, T0 + 2, 1);
        rd_a8(As[1], arow0, lrow, lkg, a);
        rd_b4(Bs[1], b0r, lrow, lkg, b);
        WAIT4(); PBAR(); SBAR();
        MFMA_Q(0, 0);
        PBAR();
        // P6: stage B(T0+2)h0; read b1(T1); Q(0,1)
        if (more) STG_B_H(0, T0 + 2, 0);
        rd_b4(Bs[1], b1r, lrow, lkg, b);
        WAIT4(); PBAR(); SBAR();
        MFMA_Q(0, 1);
        PBAR();
        // P7: stage B(T0+2)h1; read a1(T1); Q(1,1)
        if (more) STG_B_H(0, T0 + 2, 1);
        rd_a8(As[1], arow0 + 64, lrow, lkg, a);
        WAIT4(); PBAR(); SBAR();
        MFMA_Q(1, 1);
        PBAR();
        // P8: stage A(T1+2)h0; re-read b0(T1); Q(1,0)
        rd_b4(Bs[1], b0r, lrow, lkg, b);
        if (more) { STG_A_H(1, T1 + 2, 0); WAIT4(); } else { WAIT0(); }
        PBAR(); SBAR();
        MFMA_Q(1, 0);
        PBAR();
    }
#undef STG_A_H
#undef STG_B_H
#undef WAIT4
#undef WAIT0
#undef PBAR
#undef SBAR
#undef MFMA_Q

    // C write: row = bm + arow0 + idx*16 + lkg*4 + r;
    // col(j) = bn + (j>>1)*128 + wc*32 + (j&1)*16 + lrow  (b0->cols 0,1; b1->2,3)
    const int crow = bm + arow0 + lkg * 4;
    #pragma unroll
    for (int i = 0; i < 8; ++i) {
        #pragma unroll
        for (int j = 0; j < 4; ++j) {
            int ccol = bn + (j >> 1) * 128 + wc * 32 + (j & 1) * 16 + lrow;
            float bv = bias[ccol];
            float* Cp = C + (size_t)(crow + 16 * i) * ldc + ccol;
            #pragma unroll
            for (int r = 0; r < 4; ++r)
                Cp[(size_t)r * ldc] = acc[i][j][r] + bv;
        }
    }
}

// ---------------------------------------------------------------------------
// Reduce XSK split-K partials -> xdbl (fp32) + xdbl_b (bf16)
// ---------------------------------------------------------------------------
__global__ __launch_bounds__(256) void reduce_xdbl(const float* __restrict__ part,
                                                   float* __restrict__ xdbl,
                                                   unsigned short* __restrict__ xdbl_b)
{
    int i = blockIdx.x * 256 + threadIdx.x;     // over 2048*128/4 = 65536
    float4 s = ((const float4*)part)[i];
    #pragma unroll
    for (int z = 1; z < XSK; ++z) {
        float4 v = ((const float4*)part)[(size_t)z * (M_ROWS * XPAD / 4) + i];
        s.x += v.x; s.y += v.y; s.z += v.z; s.w += v.w;
    }
    ((float4*)xdbl)[i] = s;
    ushort4 o;
    o.x = f2bf(s.x); o.y = f2bf(s.y); o.z = f2bf(s.z); o.w = f2bf(s.w);
    ((ushort4*)xdbl_b)[i] = o;
}

// ---------------------------------------------------------------------------
// Causal depthwise conv1d (k=4) + bias + SiLU; bf16 in (xzb) -> bf16 out (xcb)
// ---------------------------------------------------------------------------
__global__ __launch_bounds__(256) void conv_silu_kernel(const unsigned short* __restrict__ xzb,
                                                        const float* __restrict__ cw,
                                                        const float* __restrict__ cb,
                                                        unsigned short* __restrict__ xcb)
{
    int idx = blockIdx.x * 256 + threadIdx.x;
    int d = idx & (D_INNER - 1);
    int m = idx >> 11;
    int l = m & (SEQ - 1);
    int b = m >> 10;
    float w0 = cw[d * 4 + 0], w1 = cw[d * 4 + 1], w2 = cw[d * 4 + 2], w3 = cw[d * 4 + 3];
    float s = cb[d];
    const unsigned short* base = xzb + ((size_t)b * SEQ) * (2 * D_INNER) + d;
    if (l - 3 >= 0) s += bf2f(base[(size_t)(l - 3) * (2 * D_INNER)]) * w0;
    if (l - 2 >= 0) s += bf2f(base[(size_t)(l - 2) * (2 * D_INNER)]) * w1;
    if (l - 1 >= 0) s += bf2f(base[(size_t)(l - 1) * (2 * D_INNER)]) * w2;
    s += bf2f(base[(size_t)l * (2 * D_INNER)]) * w3;
    float v = s * sigmoidf_(s);
    xcb[(size_t)m * D_INNER + d] = f2bf(v);
}

// ---------------------------------------------------------------------------
// Chunk-parallel selective scan (linear recurrence decomposition).
// ---------------------------------------------------------------------------
__global__ __launch_bounds__(256) void scan_partial(const unsigned short* __restrict__ dtb,
                                                    const float* __restrict__ xdbl,
                                                    const unsigned short* __restrict__ xcb,
                                                    const float* __restrict__ A_log,
                                                    float* __restrict__ H,
                                                    float* __restrict__ P)
{
    const int tid = threadIdx.x;
    const int b = blockIdx.x & 1;
    const int c = (blockIdx.x >> 1) & (NC - 1);
    const int d = ((blockIdx.x >> 6) << 8) + tid;

    __shared__ float Bsm[LC][8];
    {
        int r = tid >> 3, n = tid & 7;
        Bsm[r][n] = xdbl[(size_t)(b * SEQ + c * LC + r) * XPAD + DT_RANK + n];
    }
    __syncthreads();

    float An[8];
    #pragma unroll
    for (int n = 0; n < 8; ++n) An[n] = -__expf(A_log[d * 8 + n]);
    float h[8] = {0.f,0.f,0.f,0.f,0.f,0.f,0.f,0.f};
    float p[8] = {1.f,1.f,1.f,1.f,1.f,1.f,1.f,1.f};

    const unsigned short* dtp = dtb + (size_t)(b * SEQ + c * LC) * D_INNER + d;
    const unsigned short* xcp = xcb + (size_t)(b * SEQ + c * LC) * D_INNER + d;
    for (int l = 0; l < LC; ++l) {
        float dtv = bf2f(dtp[(size_t)l * D_INNER]);
        float ux  = dtv * bf2f(xcp[(size_t)l * D_INNER]);
        #pragma unroll
        for (int n = 0; n < 8; ++n) {
            float dA = __expf(dtv * An[n]);
            h[n] = dA * h[n] + Bsm[l][n] * ux;
            p[n] *= dA;
        }
    }
    size_t base = (size_t)((b * NC + c) * 8) * D_INNER + d;
    #pragma unroll
    for (int n = 0; n < 8; ++n) {
        H[base + (size_t)n * D_INNER] = h[n];
        P[base + (size_t)n * D_INNER] = p[n];
    }
}

__global__ __launch_bounds__(256) void scan_combine(const float* __restrict__ H,
                                                    float* __restrict__ P /* -> h0 */)
{
    int idx = blockIdx.x * 256 + threadIdx.x;   // 32768 = 2*8*2048
    int d = idx & (D_INNER - 1);
    int n = (idx >> 11) & 7;
    int b = idx >> 14;
    float hp = 0.f;
    for (int c = 0; c < NC; ++c) {
        size_t base = (size_t)((b * NC + c) * 8 + n) * D_INNER + d;
        float Pv = P[base], Hv = H[base];
        P[base] = hp;
        hp = Pv * hp + Hv;
    }
}

__global__ __launch_bounds__(256) void scan_final(const unsigned short* __restrict__ dtb,
                                                  const float* __restrict__ xdbl,
                                                  const unsigned short* __restrict__ xcb,
                                                  const unsigned short* __restrict__ xzb,
                                                  const float* __restrict__ A_log,
                                                  const float* __restrict__ Dp,
                                                  const float* __restrict__ h0,
                                                  unsigned short* __restrict__ yb)
{
    const int tid = threadIdx.x;
    const int b = blockIdx.x & 1;
    const int c = (blockIdx.x >> 1) & (NC - 1);
    const int d = ((blockIdx.x >> 6) << 8) + tid;

    __shared__ float Bsm[LC][8];
    __shared__ float Csm[LC][8];
    {
        int r = tid >> 3, n = tid & 7;
        size_t xrow = (size_t)(b * SEQ + c * LC + r) * XPAD;
        Bsm[r][n] = xdbl[xrow + DT_RANK + n];
        Csm[r][n] = xdbl[xrow + DT_RANK + 8 + n];
    }
    __syncthreads();

    float An[8], h[8];
    size_t base = (size_t)((b * NC + c) * 8) * D_INNER + d;
    #pragma unroll
    for (int n = 0; n < 8; ++n) {
        An[n] = -__expf(A_log[d * 8 + n]);
        h[n] = h0[base + (size_t)n * D_INNER];
    }
    const float Dv = Dp[d];

    const unsigned short* dtp = dtb + (size_t)(b * SEQ + c * LC) * D_INNER + d;
    const unsigned short* xcp = xcb + (size_t)(b * SEQ + c * LC) * D_INNER + d;
    const unsigned short* zp  = xzb + (size_t)(b * SEQ + c * LC) * (2 * D_INNER) + D_INNER + d;
    unsigned short* ybp = yb + (size_t)(b * SEQ + c * LC) * D_INNER + d;

    for (int l = 0; l < LC; ++l) {
        float dtv = bf2f(dtp[(size_t)l * D_INNER]);
        float xcv = bf2f(xcp[(size_t)l * D_INNER]);
        float zv  = bf2f(zp[(size_t)l * (2 * D_INNER)]);
        float ux = dtv * xcv;
        float acc = 0.f;
        #pragma unroll
        for (int n = 0; n < 8; ++n) {
            float dA = __expf(dtv * An[n]);
            h[n] = dA * h[n] + Bsm[l][n] * ux;
            acc += h[n] * Csm[l][n];
        }
        float yv = (acc + xcv * Dv) * (zv * sigmoidf_(zv));
        ybp[(size_t)l * D_INNER] = f2bf(yv);
    }
}

// ---------------------------------------------------------------------------
// LayerNorm (1024). NEXTRA extras summed with xin. Emits fp32 + bf16.
// ---------------------------------------------------------------------------
template<int NEXTRA>
__global__ __launch_bounds__(256) void ln_kernel(const float* __restrict__ e0,
                                                 const float* __restrict__ e1,
                                                 const float* __restrict__ xin,
                                                 float* __restrict__ xout,
                                                 unsigned short* __restrict__ xbout,
                                                 const float* __restrict__ g,
                                                 const float* __restrict__ bb)
{
    int m = blockIdx.x;
    int t = threadIdx.x;
    float4 v = ((const float4*)(xin + (size_t)m * D_MODEL))[t];
    if (NEXTRA >= 1) {
        float4 e = ((const float4*)(e0 + (size_t)m * D_MODEL))[t];
        v.x += e.x; v.y += e.y; v.z += e.z; v.w += e.w;
    }
    if (NEXTRA >= 2) {
        float4 e = ((const float4*)(e1 + (size_t)m * D_MODEL))[t];
        v.x += e.x; v.y += e.y; v.z += e.z; v.w += e.w;
    }
    float s  = v.x + v.y + v.z + v.w;
    float s2 = v.x * v.x + v.y * v.y + v.z * v.z + v.w * v.w;
    for (int off = 32; off; off >>= 1) {
        s  += __shfl_down(s, off);
        s2 += __shfl_down(s2, off);
    }
    __shared__ float red[8];
    int wid = t >> 6, lane = t & 63;
    if (lane == 0) { red[wid] = s; red[wid + 4] = s2; }
    __syncthreads();
    if (t == 0) {
        float a  = red[0] + red[1] + red[2] + red[3];
        float b2 = red[4] + red[5] + red[6] + red[7];
        float mu = a * (1.f / D_MODEL);
        red[0] = mu;
        red[4] = b2 * (1.f / D_MODEL) - mu * mu;
    }
    __syncthreads();
    float mu = red[0];
    float rs = rsqrtf(red[4] + 1e-5f);
    float4 gg = ((const float4*)g)[t];
    float4 bv = ((const float4*)bb)[t];
    float4 o;
    o.x = (v.x - mu) * rs * gg.x + bv.x;
    o.y = (v.y - mu) * rs * gg.y + bv.y;
    o.z = (v.z - mu) * rs * gg.z + bv.z;
    o.w = (v.w - mu) * rs * gg.w + bv.w;
    ((float4*)(xout + (size_t)m * D_MODEL))[t] = o;
    ushort4 ob;
    ob.x = f2bf(o.x); ob.y = f2bf(o.y); ob.z = f2bf(o.z); ob.w = f2bf(o.w);
    ((ushort4*)(xbout + (size_t)m * D_MODEL))[t] = ob;
}

// ---------------------------------------------------------------------------
extern "C" void kernel_launch(void* const* d_in, const int* in_sizes, int n_in,
                              void* d_out, int out_size, void* d_ws, size_t ws_size,
                              hipStream_t stream)
{
    const int*   ids      = (const int*)d_in[0];
    const float* embed    = (const float*)d_in[1];
    const float* in_proj  = (const float*)d_in[2];
    const float* conv_w   = (const float*)d_in[3];
    const float* conv_b   = (const float*)d_in[4];
    const float* x_proj   = (const float*)d_in[5];
    const float* dt_w     = (const float*)d_in[6];
    const float* dt_b     = (const float*)d_in[7];
    const float* A_log    = (const float*)d_in[8];
    const float* Dp       = (const float*)d_in[9];
    const float* out_proj = (const float*)d_in[10];
    const float* ln_g     = (const float*)d_in[11];
    const float* ln_b     = (const float*)d_in[12];
    const float* fn_g     = (const float*)d_in[13];
    const float* fn_b     = (const float*)d_in[14];
    const float* fc_w     = (const float*)d_in[15];
    const float* fc_b     = (const float*)d_in[16];
    float* logits = (float*)d_out;

    // ---- workspace layout (fp32 first, then bf16) ----
    float* ws = (float*)d_ws;
    float* x     = ws;                                   // 2048*1024
    float* xdbl  = x + (size_t)M_ROWS * D_MODEL;         // 2048*128
    float* tmp   = xdbl + (size_t)M_ROWS * XPAD;         // 2048*1024 (H/P alias)
    float* xpart = tmp + (size_t)M_ROWS * D_MODEL;       // XSK*2048*128 (= 2*2048*1024)

    float* Hbuf = tmp;
    float* Pbuf = tmp + (size_t)BATCH * NC * D_STATE * D_INNER;
    float* opart = xpart;   // out_proj partials alias xpart (both 4.19M floats)

    unsigned short* xb     = (unsigned short*)(xpart + (size_t)XSK * M_ROWS * XPAD);
    unsigned short* yb     = xb + (size_t)M_ROWS * D_MODEL;
    unsigned short* xzb    = yb + (size_t)M_ROWS * D_INNER;
    unsigned short* xcb    = xzb + (size_t)M_ROWS * 2 * D_INNER;
    unsigned short* dtb    = xcb + (size_t)M_ROWS * D_INNER;
    unsigned short* xdbl_b = dtb + (size_t)M_ROWS * D_INNER;
    unsigned short* wb_in  = xdbl_b + (size_t)M_ROWS * XPAD;
    unsigned short* wb_out = wb_in + (size_t)NLAYERS * 2 * D_INNER * D_MODEL;
    unsigned short* wb_fc  = wb_out + (size_t)NLAYERS * D_MODEL * D_INNER;
    unsigned short* wb_x   = wb_fc + (size_t)VOCAB * D_MODEL;
    unsigned short* wb_dt  = wb_x + (size_t)NLAYERS * XPAD * D_INNER;

    // ---- weight casts ----
    {
        int n4 = NLAYERS * 2 * D_INNER * D_MODEL / 4;
        cast_kernel<<<(n4 + 255) / 256, 256, 0, stream>>>(in_proj, wb_in, n4);
        n4 = NLAYERS * D_MODEL * D_INNER / 4;
        cast_kernel<<<(n4 + 255) / 256, 256, 0, stream>>>(out_proj, wb_out, n4);
        n4 = VOCAB * D_MODEL / 4;
        cast_kernel<<<(n4 + 255) / 256, 256, 0, stream>>>(fc_w, wb_fc, n4);
        n4 = NLAYERS * D_INNER * DT_RANK / 4;
        cast_kernel<<<(n4 + 255) / 256, 256, 0, stream>>>(dt_w, wb_dt, n4);
        n4 = NLAYERS * XPAD * D_INNER / 4;
        cast_pad_xproj<<<(n4 + 255) / 256, 256, 0, stream>>>(x_proj, wb_x);
    }

    // ---- embedding (fp32 + bf16) ----
    gather_kernel<<<M_ROWS, 256, 0, stream>>>(ids, embed, x, xb);

    for (int i = 0; i < NLAYERS; ++i) {
        const unsigned short* W_in_b  = wb_in + (size_t)i * 2 * D_INNER * D_MODEL;
        const unsigned short* W_out_b = wb_out + (size_t)i * D_MODEL * D_INNER;
        const unsigned short* W_x_b   = wb_x + (size_t)i * XPAD * D_INNER;
        const unsigned short* W_dt_b  = wb_dt + (size_t)i * D_INNER * DT_RANK;
        const float* cw    = conv_w + (size_t)i * D_INNER * 4;
        const float* cb    = conv_b + (size_t)i * D_INNER;
        const float* b_dt  = dt_b + (size_t)i * D_INNER;
        const float* Al    = A_log + (size_t)i * D_INNER * D_STATE;
        const float* Dl    = Dp + (size_t)i * D_INNER;
        const float* g     = ln_g + (size_t)i * D_MODEL;
        const float* bb    = ln_b + (size_t)i * D_MODEL;

        // xz(bf16) = x @ in_proj^T   (2048 x 4096, K=1024)   grid 16x32
        gemm_bf16_nt<1><<<dim3(M_ROWS / 128, 2 * D_INNER / 128), 256, 0, stream>>>(
            xb, D_MODEL, W_in_b, D_MODEL, xzb, 2 * D_INNER, D_MODEL, nullptr);

        // xc(bf16) = silu(conv(xz[:, :2048]) + cb)
        conv_silu_kernel<<<(M_ROWS * D_INNER) / 256, 256, 0, stream>>>(xzb, cw, cb, xcb);

        // x_dbl partials: (2048 x 128, K=2048 split XSK x 128)  grid 16x1x16
        gemm_bf16_nt<0><<<dim3(M_ROWS / 128, 1, XSK), 256, 0, stream>>>(
            xcb, D_INNER, W_x_b, D_INNER, xpart, XPAD, D_INNER / XSK, nullptr);
        reduce_xdbl<<<(M_ROWS * XPAD / 4) / 256, 256, 0, stream>>>(xpart, xdbl, xdbl_b);

        // dt(bf16) = softplus(x_dbl[:, :64] @ dt_w^T + b_dt)  (2048x2048, K=64) grid 16x16
        gemm_bf16_nt<3><<<dim3(M_ROWS / 128, D_INNER / 128), 256, 0, stream>>>(
            xdbl_b, XPAD, W_dt_b, DT_RANK, dtb, D_INNER, DT_RANK, b_dt);

        // chunk-parallel scan -> yb (bf16)
        scan_partial<<<BATCH * NC * (D_INNER / 256), 256, 0, stream>>>(
            dtb, xdbl, xcb, Al, Hbuf, Pbuf);
        scan_combine<<<(BATCH * D_STATE * D_INNER) / 256, 256, 0, stream>>>(Hbuf, Pbuf);
        scan_final<<<BATCH * NC * (D_INNER / 256), 256, 0, stream>>>(
            dtb, xdbl, xcb, xzb, Al, Dl, Pbuf, yb);

        // out_proj partials: (2048 x 1024, K=2048 split 2 x 1024)  grid 16x8x2
        gemm_bf16_nt<0><<<dim3(M_ROWS / 128, D_MODEL / 128, OSK), 256, 0, stream>>>(
            yb, D_INNER, W_out_b, D_INNER, opart, D_MODEL, D_INNER / OSK, nullptr);

        // x = LN(opart0 + opart1 + x)  (fp32 + bf16)
        ln_kernel<2><<<M_ROWS, 256, 0, stream>>>(
            opart, opart + (size_t)M_ROWS * D_MODEL, x, x, xb, g, bb);
    }

    // final LN -> tmp + xb
    ln_kernel<0><<<M_ROWS, 256, 0, stream>>>(nullptr, nullptr, x, tmp, xb, fn_g, fn_b);

    // logits = xf @ fc_w^T + fc_b   (2048 x 32000, K=1024)  8-phase 256² grid 8x125
    gemm_bf16_8ph<<<dim3(M_ROWS / 256, VOCAB / 256), 512, 0, stream>>>(
        xb, D_MODEL, wb_fc, D_MODEL, logits, VOCAB, D_MODEL, fc_b);
}

// Round 11
// 893.499 us; speedup vs baseline: 1.1300x; 1.0063x over previous
//
#include <hip/hip_runtime.h>
#include <cstddef>
#include <cstdint>

#define D_MODEL 1024
#define D_INNER 2048
#define DT_RANK 64
#define D_STATE 8
#define NLAYERS 4
#define BATCH 2
#define SEQ 1024
#define M_ROWS (BATCH*SEQ)   /* 2048 */
#define VOCAB 32000
#define XPAD 128             /* x_proj N padded 80 -> 128 */
#define NC 32                /* scan chunks */
#define LC 32                /* chunk length (NC*LC == SEQ) */
#define XSK 16               /* x_proj split-K factor */
#define OSK 2                /* out_proj split-K factor */

typedef __attribute__((ext_vector_type(8))) short short8;
typedef __attribute__((ext_vector_type(4))) float f32x4;

#define GPTR(p) (const __attribute__((address_space(1))) void*)(p)
#define LPTR(p) (__attribute__((address_space(3))) void*)(p)

__device__ __forceinline__ float sigmoidf_(float x) { return 1.f / (1.f + __expf(-x)); }

__device__ __forceinline__ unsigned short f2bf(float f) {
    unsigned u = __float_as_uint(f);
    u += 0x7fffu + ((u >> 16) & 1u);         // round-to-nearest-even
    return (unsigned short)(u >> 16);
}
__device__ __forceinline__ float bf2f(unsigned short u) {
    return __uint_as_float((unsigned)u << 16);
}

// ---------------------------------------------------------------------------
// fp32 -> bf16 cast (contiguous), 4 elems/thread.
// ---------------------------------------------------------------------------
__global__ __launch_bounds__(256) void cast_kernel(const float* __restrict__ in,
                                                   unsigned short* __restrict__ out, int n4)
{
    int i = blockIdx.x * 256 + threadIdx.x;
    if (i >= n4) return;
    float4 v = ((const float4*)in)[i];
    ushort4 o;
    o.x = f2bf(v.x); o.y = f2bf(v.y); o.z = f2bf(v.z); o.w = f2bf(v.w);
    ((ushort4*)out)[i] = o;
}

// ---------------------------------------------------------------------------
// x_proj weight: cast 4x(80,2048) fp32 -> 4x(128,2048) bf16, rows 80..127 = 0
// ---------------------------------------------------------------------------
__global__ __launch_bounds__(256) void cast_pad_xproj(const float* __restrict__ in,
                                                      unsigned short* __restrict__ out)
{
    int i = blockIdx.x * 256 + threadIdx.x;     // over 4*128*2048/4 = 262144
    if (i >= NLAYERS * XPAD * D_INNER / 4) return;
    int col4 = i & (D_INNER / 4 - 1);           // 512 col-groups
    int row = (i >> 9) & (XPAD - 1);
    int layer = i >> 16;
    ushort4 o = {0, 0, 0, 0};
    if (row < 80) {
        float4 v = ((const float4*)(in + ((size_t)layer * 80 + row) * D_INNER))[col4];
        o.x = f2bf(v.x); o.y = f2bf(v.y); o.z = f2bf(v.z); o.w = f2bf(v.w);
    }
    ((ushort4*)out)[i] = o;
}

// ---------------------------------------------------------------------------
// Embedding gather -> x (fp32) and xb (bf16)
// ---------------------------------------------------------------------------
__global__ __launch_bounds__(256) void gather_kernel(const int* __restrict__ ids,
                                                     const float* __restrict__ embed,
                                                     float* __restrict__ x,
                                                     unsigned short* __restrict__ xb)
{
    int m = blockIdx.x;
    int t = threadIdx.x;
    int id = ids[m];
    float4 v = ((const float4*)(embed + (size_t)id * D_MODEL))[t];
    ((float4*)(x + (size_t)m * D_MODEL))[t] = v;
    ushort4 o;
    o.x = f2bf(v.x); o.y = f2bf(v.y); o.z = f2bf(v.z); o.w = f2bf(v.w);
    ((ushort4*)(xb + (size_t)m * D_MODEL))[t] = o;
}

// ---------------------------------------------------------------------------
// bf16 MFMA GEMM  C[M,N] = A[M,K] * B[N,K]^T
// 128x128 tile, BK=32, 4 waves. Double-buffered LDS, counted-vmcnt pipeline.
// EPI: 0 fp32 (+splitK z-offset) | 1 bf16 | 2 fp32 +bias | 3 bf16 softplus(v+bias)
// ---------------------------------------------------------------------------
template<int EPI>
__global__ __launch_bounds__(256) void gemm_bf16_nt(const unsigned short* __restrict__ A, int lda,
                                                    const unsigned short* __restrict__ B, int ldb,
                                                    void* __restrict__ Cv, int ldc,
                                                    int K, const float* __restrict__ bias)
{
    __shared__ unsigned short As[2][128 * 32];
    __shared__ unsigned short Bs[2][128 * 32];
    const int tid = threadIdx.x;

    const int gm = gridDim.x;
    const int bid = blockIdx.y * gm + blockIdx.x;
    const int q = (gm * gridDim.y) >> 3;           // nwg % 8 == 0 guaranteed
    const int swz = (bid & 7) * q + (bid >> 3);
    const int bm = (swz % gm) * 128, bn = (swz / gm) * 128;

    const int wid = tid >> 6, lane = tid & 63;
    const int wm = (wid >> 1) * 64, wn = (wid & 1) * 64;
    const int lrow = lane & 15, lkg = lane >> 4;

    const int srow = tid >> 2;                               // 0..63
    const int ksrc = ((tid & 3) ^ ((srow >> 1) & 3)) * 8;    // elems, const/thread
    const size_t kz = (size_t)blockIdx.z * K;
    const unsigned short* Ag = A + (size_t)(bm + srow) * lda + kz + ksrc;
    const unsigned short* Bg = B + (size_t)(bn + srow) * ldb + kz + ksrc;
    const size_t r64a = (size_t)64 * lda;
    const size_t r64b = (size_t)64 * ldb;

#define STAGE(buf, koff)                                                                              \
    do {                                                                                              \
        __builtin_amdgcn_global_load_lds(GPTR(Ag + (koff)),        LPTR(&As[buf][tid * 8]), 16, 0, 0);\
        __builtin_amdgcn_global_load_lds(GPTR(Ag + r64a + (koff)), LPTR(&As[buf][2048 + tid * 8]), 16, 0, 0);\
        __builtin_amdgcn_global_load_lds(GPTR(Bg + (koff)),        LPTR(&Bs[buf][tid * 8]), 16, 0, 0);\
        __builtin_amdgcn_global_load_lds(GPTR(Bg + r64b + (koff)), LPTR(&Bs[buf][2048 + tid * 8]), 16, 0, 0);\
    } while (0)

    f32x4 acc[4][4];
    #pragma unroll
    for (int i = 0; i < 4; ++i)
        #pragma unroll
        for (int j = 0; j < 4; ++j)
            acc[i][j] = f32x4{0.f, 0.f, 0.f, 0.f};

    STAGE(0, 0);                      // prologue

    int cur = 0;
    for (int k0 = 0; k0 < K; k0 += 32) {
        if (k0 + 32 < K) {
            STAGE(cur ^ 1, k0 + 32);                             // next tile in flight
            asm volatile("s_waitcnt vmcnt(4)" ::: "memory");     // cur's 4 landed
        } else {
            asm volatile("s_waitcnt vmcnt(0)" ::: "memory");     // final drain
        }
        __builtin_amdgcn_s_barrier();          // publish cur to all waves
        __builtin_amdgcn_sched_barrier(0);     // pin: no hoisting above the wait

        short8 af[4], bf[4];
        #pragma unroll
        for (int i = 0; i < 4; ++i) {
            int ra = wm + 16 * i + lrow;
            int pa = lkg ^ ((ra >> 1) & 3);
            af[i] = *(const short8*)(&As[cur][ra * 32 + pa * 8]);
            int rb = wn + 16 * i + lrow;
            int pb = lkg ^ ((rb >> 1) & 3);
            bf[i] = *(const short8*)(&Bs[cur][rb * 32 + pb * 8]);
        }
        __builtin_amdgcn_s_setprio(1);
        #pragma unroll
        for (int i = 0; i < 4; ++i)
            #pragma unroll
            for (int j = 0; j < 4; ++j)
                acc[i][j] = __builtin_amdgcn_mfma_f32_16x16x32_bf16(af[i], bf[j], acc[i][j], 0, 0, 0);
        __builtin_amdgcn_s_setprio(0);

        __builtin_amdgcn_s_barrier();          // all reads of cur done before overwrite
        cur ^= 1;
    }
#undef STAGE

    const int crow = bm + wm + lkg * 4;
    const int ccol = bn + wn + lrow;
    #pragma unroll
    for (int i = 0; i < 4; ++i) {
        #pragma unroll
        for (int j = 0; j < 4; ++j) {
            float bv = (EPI == 2 || EPI == 3) ? bias[ccol + 16 * j] : 0.f;
            #pragma unroll
            for (int r = 0; r < 4; ++r) {
                float v = acc[i][j][r] + bv;
                size_t off = (size_t)(crow + 16 * i + r) * ldc + ccol + 16 * j;
                if (EPI == 0) {
                    ((float*)Cv)[(size_t)blockIdx.z * M_ROWS * ldc + off] = v;
                } else if (EPI == 2) {
                    ((float*)Cv)[off] = v;
                } else {
                    if (EPI == 3) v = (v > 20.f) ? v : log1pf(__expf(v));
                    ((unsigned short*)Cv)[off] = f2bf(v);
                }
            }
        }
    }
}

// ---------------------------------------------------------------------------
// 8-phase 256x256 GEMM (m201 template). 512 thr = 8 waves (2M x 4N); 2 K-tiles
// (BK=64)/iter; LDS 128 KiB. b0 kept in a 2nd register set (b0s) so Q(1,0)
// has no LDS re-read -> B halves free by P2/P6. Stage schedule (iter i):
//   P3:B(T0+2)h0  P4:A(T0+2)h0  P5:A(T0+2)h1+B(T0+2)h1  P7:B(T1+2)h0
//   P8:B(T1+2)h1+A(T1+2)h0+A(T1+2)h1
// Min stage->first-read distance: 3 phases (P5->next P1). Waits ONLY at
// P4 (vmcnt(4): outstanding = P3+P4; covers prev P7/P8 = T1 data) and
// P8 (vmcnt(8): outstanding = P7+P8; covers P3-P5 = T0+2 data).
// Overwrite safety: every stage is >=1 end-barrier after its slot's last read.
// T2 swizzle p = u ^ (row&7); linear gload dest + inverse-swizzled source.
// ---------------------------------------------------------------------------
__device__ __forceinline__ void rd_a8(const unsigned short* S, int base, int lrow, int lkg, short8 a[4][2]) {
    #pragma unroll
    for (int i = 0; i < 4; ++i)
        #pragma unroll
        for (int kk = 0; kk < 2; ++kk) {
            int row = base + i * 16 + lrow;
            int p = (kk * 4 + lkg) ^ (lrow & 7);
            a[i][kk] = *(const short8*)(S + row * 64 + p * 8);
        }
}
__device__ __forceinline__ void rd_b4(const unsigned short* S, int base, int lrow, int lkg, short8 b[2][2]) {
    #pragma unroll
    for (int j = 0; j < 2; ++j)
        #pragma unroll
        for (int kk = 0; kk < 2; ++kk) {
            int row = base + j * 16 + lrow;
            int p = (kk * 4 + lkg) ^ (lrow & 7);
            b[j][kk] = *(const short8*)(S + row * 64 + p * 8);
        }
}

__global__ __launch_bounds__(512) void gemm_bf16_8ph(const unsigned short* __restrict__ A, int lda,
                                                     const unsigned short* __restrict__ B, int ldb,
                                                     float* __restrict__ C, int ldc,
                                                     int K, const float* __restrict__ bias)
{
    __shared__ unsigned short As[2][256 * 64];
    __shared__ unsigned short Bs[2][256 * 64];
    const int tid = threadIdx.x;

    const int gm = gridDim.x;
    const int bid = blockIdx.y * gm + blockIdx.x;
    const int q = (gm * gridDim.y) >> 3;
    const int swz = (bid & 7) * q + (bid >> 3);
    const int bm = (swz % gm) * 256, bn = (swz / gm) * 256;

    const int wid = tid >> 6, lane = tid & 63;
    const int wr = wid >> 2, wc = wid & 3;
    const int arow0 = wr * 128;                 // wave's A half
    const int b0r = wc * 32, b1r = 128 + wc * 32;
    const int lrow = lane & 15, lkg = lane >> 4;

    const int sg = tid >> 3, su = tid & 7;      // staging row-in-64 / unit
    const int ksrc = (su ^ (sg & 7)) * 8;       // inverse-swizzled global src
    const unsigned short* Ag = A + (size_t)(bm + sg) * lda + ksrc;
    const unsigned short* Bg = B + (size_t)(bn + sg) * ldb + ksrc;

#define STG_A_H(buf, kt, h) do {                                                                   \
    __builtin_amdgcn_global_load_lds(GPTR(Ag + (size_t)(kt) * 64 + (size_t)((h) * 128) * lda),     \
                                     LPTR(&As[buf][(h) * 8192 + tid * 8]), 16, 0, 0);              \
    __builtin_amdgcn_global_load_lds(GPTR(Ag + (size_t)(kt) * 64 + (size_t)((h) * 128 + 64) * lda),\
                                     LPTR(&As[buf][(h) * 8192 + 4096 + tid * 8]), 16, 0, 0);       \
} while (0)
#define STG_B_H(buf, kt, h) do {                                                                   \
    __builtin_amdgcn_global_load_lds(GPTR(Bg + (size_t)(kt) * 64 + (size_t)((h) * 128) * ldb),     \
                                     LPTR(&Bs[buf][(h) * 8192 + tid * 8]), 16, 0, 0);              \
    __builtin_amdgcn_global_load_lds(GPTR(Bg + (size_t)(kt) * 64 + (size_t)((h) * 128 + 64) * ldb),\
                                     LPTR(&Bs[buf][(h) * 8192 + 4096 + tid * 8]), 16, 0, 0);       \
} while (0)
#define WAITN(n) asm volatile("s_waitcnt vmcnt(" #n ")" ::: "memory")
#define PBAR() __builtin_amdgcn_s_barrier()
#define SBAR() __builtin_amdgcn_sched_barrier(0)
#define MFMA_Q(QA, BH, BARR) do {                                                                  \
    __builtin_amdgcn_s_setprio(1);                                                                 \
    _Pragma("unroll") for (int i = 0; i < 4; ++i)                                                  \
    _Pragma("unroll") for (int j = 0; j < 2; ++j)                                                  \
    _Pragma("unroll") for (int kk = 0; kk < 2; ++kk)                                               \
        acc[(QA) * 4 + i][(BH) * 2 + j] =                                                          \
            __builtin_amdgcn_mfma_f32_16x16x32_bf16(a[i][kk], BARR[j][kk],                         \
                                                    acc[(QA) * 4 + i][(BH) * 2 + j], 0, 0, 0);     \
    __builtin_amdgcn_s_setprio(0);                                                                 \
} while (0)

    f32x4 acc[8][4];
    #pragma unroll
    for (int i = 0; i < 8; ++i)
        #pragma unroll
        for (int j = 0; j < 4; ++j)
            acc[i][j] = f32x4{0.f, 0.f, 0.f, 0.f};

    short8 a[4][2], b[2][2], b0s[2][2];
    const int NT = K >> 6;        // 16 K-tiles
    const int NI = NT >> 1;       // 8 iterations

    // prologue: stage T0 and T1 fully (16 loads); wait T0 landed (8 newest = T1).
    STG_A_H(0, 0, 0); STG_A_H(0, 0, 1); STG_B_H(0, 0, 0); STG_B_H(0, 0, 1);
    STG_A_H(1, 1, 0); STG_A_H(1, 1, 1); STG_B_H(1, 1, 0); STG_B_H(1, 1, 1);
    WAITN(8);
    PBAR();

    for (int it = 0; it < NI; ++it) {
        const int T0n = 2 * it + 2, T1n = 2 * it + 3;   // tiles to prefetch
        const bool more = (it + 1 < NI);

        // P1: read a0(T0), b0(T0)->b0s; Q(0,0)
        rd_a8(As[0], arow0, lrow, lkg, a);
        rd_b4(Bs[0], b0r, lrow, lkg, b0s);
        PBAR(); SBAR();
        MFMA_Q(0, 0, b0s);
        PBAR();
        // P2: read b1(T0); Q(0,1)
        rd_b4(Bs[0], b1r, lrow, lkg, b);
        PBAR(); SBAR();
        MFMA_Q(0, 1, b);
        PBAR();
        // P3: stage B(T0+2)h0 (Bs[0] reads done at P2); read a1(T0); Q(1,1)
        if (more) STG_B_H(0, T0n, 0);
        rd_a8(As[0], arow0 + 64, lrow, lkg, a);
        PBAR(); SBAR();
        MFMA_Q(1, 1, b);
        PBAR();
        // P4: stage A(T0+2)h0 (As[0] reads done at P3); WAIT(4) covers T1 data
        //     (staged prev P7/P8, >=4 phases old); Q(1,0) uses saved b0s.
        if (more) { STG_A_H(0, T0n, 0); WAITN(4); } else { WAITN(0); }
        PBAR(); SBAR();
        MFMA_Q(1, 0, b0s);
        PBAR();
        // P5: stage A(T0+2)h1 + B(T0+2)h1; read a0(T1), b0(T1)->b0s; Q(0,0)
        if (more) { STG_A_H(0, T0n, 1); STG_B_H(0, T0n, 1); }
        rd_a8(As[1], arow0, lrow, lkg, a);
        rd_b4(Bs[1], b0r, lrow, lkg, b0s);
        PBAR(); SBAR();
        MFMA_Q(0, 0, b0s);
        PBAR();
        // P6: read b1(T1); Q(0,1)
        rd_b4(Bs[1], b1r, lrow, lkg, b);
        PBAR(); SBAR();
        MFMA_Q(0, 1, b);
        PBAR();
        // P7: stage B(T1+2)h0 (Bs[1] reads done at P6); read a1(T1); Q(1,1)
        if (more) STG_B_H(1, T1n, 0);
        rd_a8(As[1], arow0 + 64, lrow, lkg, a);
        PBAR(); SBAR();
        MFMA_Q(1, 1, b);
        PBAR();
        // P8: stage B(T1+2)h1 + A(T1+2)h0/h1 (As[1] reads done at P7);
        //     WAIT(8): outstanding = P7+P8's 8 -> all T0+2 stages landed.
        if (more) {
            STG_B_H(1, T1n, 1); STG_A_H(1, T1n, 0); STG_A_H(1, T1n, 1);
            WAITN(8);
        } else {
            WAITN(0);
        }
        PBAR(); SBAR();
        MFMA_Q(1, 0, b0s);
        PBAR();
    }
#undef STG_A_H
#undef STG_B_H
#undef WAITN
#undef PBAR
#undef SBAR
#undef MFMA_Q

    // C write: row = bm + arow0 + i*16 + lkg*4 + r;
    // col(j) = bn + (j>>1)*128 + wc*32 + (j&1)*16 + lrow
    const int crow = bm + arow0 + lkg * 4;
    #pragma unroll
    for (int i = 0; i < 8; ++i) {
        #pragma unroll
        for (int j = 0; j < 4; ++j) {
            int ccol = bn + (j >> 1) * 128 + wc * 32 + (j & 1) * 16 + lrow;
            float bv = bias[ccol];
            float* Cp = C + (size_t)(crow + 16 * i) * ldc + ccol;
            #pragma unroll
            for (int r = 0; r < 4; ++r)
                Cp[(size_t)r * ldc] = acc[i][j][r] + bv;
        }
    }
}

// ---------------------------------------------------------------------------
// Reduce XSK split-K partials -> xdbl (fp32) + xdbl_b (bf16)
// ---------------------------------------------------------------------------
__global__ __launch_bounds__(256) void reduce_xdbl(const float* __restrict__ part,
                                                   float* __restrict__ xdbl,
                                                   unsigned short* __restrict__ xdbl_b)
{
    int i = blockIdx.x * 256 + threadIdx.x;     // over 2048*128/4 = 65536
    float4 s = ((const float4*)part)[i];
    #pragma unroll
    for (int z = 1; z < XSK; ++z) {
        float4 v = ((const float4*)part)[(size_t)z * (M_ROWS * XPAD / 4) + i];
        s.x += v.x; s.y += v.y; s.z += v.z; s.w += v.w;
    }
    ((float4*)xdbl)[i] = s;
    ushort4 o;
    o.x = f2bf(s.x); o.y = f2bf(s.y); o.z = f2bf(s.z); o.w = f2bf(s.w);
    ((ushort4*)xdbl_b)[i] = o;
}

// ---------------------------------------------------------------------------
// Causal depthwise conv1d (k=4) + bias + SiLU; bf16 in (xzb) -> bf16 out (xcb)
// ---------------------------------------------------------------------------
__global__ __launch_bounds__(256) void conv_silu_kernel(const unsigned short* __restrict__ xzb,
                                                        const float* __restrict__ cw,
                                                        const float* __restrict__ cb,
                                                        unsigned short* __restrict__ xcb)
{
    int idx = blockIdx.x * 256 + threadIdx.x;
    int d = idx & (D_INNER - 1);
    int m = idx >> 11;
    int l = m & (SEQ - 1);
    int b = m >> 10;
    float w0 = cw[d * 4 + 0], w1 = cw[d * 4 + 1], w2 = cw[d * 4 + 2], w3 = cw[d * 4 + 3];
    float s = cb[d];
    const unsigned short* base = xzb + ((size_t)b * SEQ) * (2 * D_INNER) + d;
    if (l - 3 >= 0) s += bf2f(base[(size_t)(l - 3) * (2 * D_INNER)]) * w0;
    if (l - 2 >= 0) s += bf2f(base[(size_t)(l - 2) * (2 * D_INNER)]) * w1;
    if (l - 1 >= 0) s += bf2f(base[(size_t)(l - 1) * (2 * D_INNER)]) * w2;
    s += bf2f(base[(size_t)l * (2 * D_INNER)]) * w3;
    float v = s * sigmoidf_(s);
    xcb[(size_t)m * D_INNER + d] = f2bf(v);
}

// ---------------------------------------------------------------------------
// Chunk-parallel selective scan (linear recurrence decomposition).
// ---------------------------------------------------------------------------
__global__ __launch_bounds__(256) void scan_partial(const unsigned short* __restrict__ dtb,
                                                    const float* __restrict__ xdbl,
                                                    const unsigned short* __restrict__ xcb,
                                                    const float* __restrict__ A_log,
                                                    float* __restrict__ H,
                                                    float* __restrict__ P)
{
    const int tid = threadIdx.x;
    const int b = blockIdx.x & 1;
    const int c = (blockIdx.x >> 1) & (NC - 1);
    const int d = ((blockIdx.x >> 6) << 8) + tid;

    __shared__ float Bsm[LC][8];
    {
        int r = tid >> 3, n = tid & 7;
        Bsm[r][n] = xdbl[(size_t)(b * SEQ + c * LC + r) * XPAD + DT_RANK + n];
    }
    __syncthreads();

    float An[8];
    #pragma unroll
    for (int n = 0; n < 8; ++n) An[n] = -__expf(A_log[d * 8 + n]);
    float h[8] = {0.f,0.f,0.f,0.f,0.f,0.f,0.f,0.f};
    float p[8] = {1.f,1.f,1.f,1.f,1.f,1.f,1.f,1.f};

    const unsigned short* dtp = dtb + (size_t)(b * SEQ + c * LC) * D_INNER + d;
    const unsigned short* xcp = xcb + (size_t)(b * SEQ + c * LC) * D_INNER + d;
    for (int l = 0; l < LC; ++l) {
        float dtv = bf2f(dtp[(size_t)l * D_INNER]);
        float ux  = dtv * bf2f(xcp[(size_t)l * D_INNER]);
        #pragma unroll
        for (int n = 0; n < 8; ++n) {
            float dA = __expf(dtv * An[n]);
            h[n] = dA * h[n] + Bsm[l][n] * ux;
            p[n] *= dA;
        }
    }
    size_t base = (size_t)((b * NC + c) * 8) * D_INNER + d;
    #pragma unroll
    for (int n = 0; n < 8; ++n) {
        H[base + (size_t)n * D_INNER] = h[n];
        P[base + (size_t)n * D_INNER] = p[n];
    }
}

__global__ __launch_bounds__(256) void scan_combine(const float* __restrict__ H,
                                                    float* __restrict__ P /* -> h0 */)
{
    int idx = blockIdx.x * 256 + threadIdx.x;   // 32768 = 2*8*2048
    int d = idx & (D_INNER - 1);
    int n = (idx >> 11) & 7;
    int b = idx >> 14;
    float hp = 0.f;
    for (int c = 0; c < NC; ++c) {
        size_t base = (size_t)((b * NC + c) * 8 + n) * D_INNER + d;
        float Pv = P[base], Hv = H[base];
        P[base] = hp;
        hp = Pv * hp + Hv;
    }
}

__global__ __launch_bounds__(256) void scan_final(const unsigned short* __restrict__ dtb,
                                                  const float* __restrict__ xdbl,
                                                  const unsigned short* __restrict__ xcb,
                                                  const unsigned short* __restrict__ xzb,
                                                  const float* __restrict__ A_log,
                                                  const float* __restrict__ Dp,
                                                  const float* __restrict__ h0,
                                                  unsigned short* __restrict__ yb)
{
    const int tid = threadIdx.x;
    const int b = blockIdx.x & 1;
    const int c = (blockIdx.x >> 1) & (NC - 1);
    const int d = ((blockIdx.x >> 6) << 8) + tid;

    __shared__ float Bsm[LC][8];
    __shared__ float Csm[LC][8];
    {
        int r = tid >> 3, n = tid & 7;
        size_t xrow = (size_t)(b * SEQ + c * LC + r) * XPAD;
        Bsm[r][n] = xdbl[xrow + DT_RANK + n];
        Csm[r][n] = xdbl[xrow + DT_RANK + 8 + n];
    }
    __syncthreads();

    float An[8], h[8];
    size_t base = (size_t)((b * NC + c) * 8) * D_INNER + d;
    #pragma unroll
    for (int n = 0; n < 8; ++n) {
        An[n] = -__expf(A_log[d * 8 + n]);
        h[n] = h0[base + (size_t)n * D_INNER];
    }
    const float Dv = Dp[d];

    const unsigned short* dtp = dtb + (size_t)(b * SEQ + c * LC) * D_INNER + d;
    const unsigned short* xcp = xcb + (size_t)(b * SEQ + c * LC) * D_INNER + d;
    const unsigned short* zp  = xzb + (size_t)(b * SEQ + c * LC) * (2 * D_INNER) + D_INNER + d;
    unsigned short* ybp = yb + (size_t)(b * SEQ + c * LC) * D_INNER + d;

    for (int l = 0; l < LC; ++l) {
        float dtv = bf2f(dtp[(size_t)l * D_INNER]);
        float xcv = bf2f(xcp[(size_t)l * D_INNER]);
        float zv  = bf2f(zp[(size_t)l * (2 * D_INNER)]);
        float ux = dtv * xcv;
        float acc = 0.f;
        #pragma unroll
        for (int n = 0; n < 8; ++n) {
            float dA = __expf(dtv * An[n]);
            h[n] = dA * h[n] + Bsm[l][n] * ux;
            acc += h[n] * Csm[l][n];
        }
        float yv = (acc + xcv * Dv) * (zv * sigmoidf_(zv));
        ybp[(size_t)l * D_INNER] = f2bf(yv);
    }
}

// ---------------------------------------------------------------------------
// LayerNorm (1024). NEXTRA extras summed with xin. Emits fp32 + bf16.
// ---------------------------------------------------------------------------
template<int NEXTRA>
__global__ __launch_bounds__(256) void ln_kernel(const float* __restrict__ e0,
                                                 const float* __restrict__ e1,
                                                 const float* __restrict__ xin,
                                                 float* __restrict__ xout,
                                                 unsigned short* __restrict__ xbout,
                                                 const float* __restrict__ g,
                                                 const float* __restrict__ bb)
{
    int m = blockIdx.x;
    int t = threadIdx.x;
    float4 v = ((const float4*)(xin + (size_t)m * D_MODEL))[t];
    if (NEXTRA >= 1) {
        float4 e = ((const float4*)(e0 + (size_t)m * D_MODEL))[t];
        v.x += e.x; v.y += e.y; v.z += e.z; v.w += e.w;
    }
    if (NEXTRA >= 2) {
        float4 e = ((const float4*)(e1 + (size_t)m * D_MODEL))[t];
        v.x += e.x; v.y += e.y; v.z += e.z; v.w += e.w;
    }
    float s  = v.x + v.y + v.z + v.w;
    float s2 = v.x * v.x + v.y * v.y + v.z * v.z + v.w * v.w;
    for (int off = 32; off; off >>= 1) {
        s  += __shfl_down(s, off);
        s2 += __shfl_down(s2, off);
    }
    __shared__ float red[8];
    int wid = t >> 6, lane = t & 63;
    if (lane == 0) { red[wid] = s; red[wid + 4] = s2; }
    __syncthreads();
    if (t == 0) {
        float a  = red[0] + red[1] + red[2] + red[3];
        float b2 = red[4] + red[5] + red[6] + red[7];
        float mu = a * (1.f / D_MODEL);
        red[0] = mu;
        red[4] = b2 * (1.f / D_MODEL) - mu * mu;
    }
    __syncthreads();
    float mu = red[0];
    float rs = rsqrtf(red[4] + 1e-5f);
    float4 gg = ((const float4*)g)[t];
    float4 bv = ((const float4*)bb)[t];
    float4 o;
    o.x = (v.x - mu) * rs * gg.x + bv.x;
    o.y = (v.y - mu) * rs * gg.y + bv.y;
    o.z = (v.z - mu) * rs * gg.z + bv.z;
    o.w = (v.w - mu) * rs * gg.w + bv.w;
    ((float4*)(xout + (size_t)m * D_MODEL))[t] = o;
    ushort4 ob;
    ob.x = f2bf(o.x); ob.y = f2bf(o.y); ob.z = f2bf(o.z); ob.w = f2bf(o.w);
    ((ushort4*)(xbout + (size_t)m * D_MODEL))[t] = ob;
}

// ---------------------------------------------------------------------------
extern "C" void kernel_launch(void* const* d_in, const int* in_sizes, int n_in,
                              void* d_out, int out_size, void* d_ws, size_t ws_size,
                              hipStream_t stream)
{
    const int*   ids      = (const int*)d_in[0];
    const float* embed    = (const float*)d_in[1];
    const float* in_proj  = (const float*)d_in[2];
    const float* conv_w   = (const float*)d_in[3];
    const float* conv_b   = (const float*)d_in[4];
    const float* x_proj   = (const float*)d_in[5];
    const float* dt_w     = (const float*)d_in[6];
    const float* dt_b     = (const float*)d_in[7];
    const float* A_log    = (const float*)d_in[8];
    const float* Dp       = (const float*)d_in[9];
    const float* out_proj = (const float*)d_in[10];
    const float* ln_g     = (const float*)d_in[11];
    const float* ln_b     = (const float*)d_in[12];
    const float* fn_g     = (const float*)d_in[13];
    const float* fn_b     = (const float*)d_in[14];
    const float* fc_w     = (const float*)d_in[15];
    const float* fc_b     = (const float*)d_in[16];
    float* logits = (float*)d_out;

    // ---- workspace layout (fp32 first, then bf16) ----
    float* ws = (float*)d_ws;
    float* x     = ws;                                   // 2048*1024
    float* xdbl  = x + (size_t)M_ROWS * D_MODEL;         // 2048*128
    float* tmp   = xdbl + (size_t)M_ROWS * XPAD;         // 2048*1024 (H/P alias)
    float* xpart = tmp + (size_t)M_ROWS * D_MODEL;       // XSK*2048*128 (= 2*2048*1024)

    float* Hbuf = tmp;
    float* Pbuf = tmp + (size_t)BATCH * NC * D_STATE * D_INNER;
    float* opart = xpart;   // out_proj partials alias xpart (both 4.19M floats)

    unsigned short* xb     = (unsigned short*)(xpart + (size_t)XSK * M_ROWS * XPAD);
    unsigned short* yb     = xb + (size_t)M_ROWS * D_MODEL;
    unsigned short* xzb    = yb + (size_t)M_ROWS * D_INNER;
    unsigned short* xcb    = xzb + (size_t)M_ROWS * 2 * D_INNER;
    unsigned short* dtb    = xcb + (size_t)M_ROWS * D_INNER;
    unsigned short* xdbl_b = dtb + (size_t)M_ROWS * D_INNER;
    unsigned short* wb_in  = xdbl_b + (size_t)M_ROWS * XPAD;
    unsigned short* wb_out = wb_in + (size_t)NLAYERS * 2 * D_INNER * D_MODEL;
    unsigned short* wb_fc  = wb_out + (size_t)NLAYERS * D_MODEL * D_INNER;
    unsigned short* wb_x   = wb_fc + (size_t)VOCAB * D_MODEL;
    unsigned short* wb_dt  = wb_x + (size_t)NLAYERS * XPAD * D_INNER;

    // ---- weight casts ----
    {
        int n4 = NLAYERS * 2 * D_INNER * D_MODEL / 4;
        cast_kernel<<<(n4 + 255) / 256, 256, 0, stream>>>(in_proj, wb_in, n4);
        n4 = NLAYERS * D_MODEL * D_INNER / 4;
        cast_kernel<<<(n4 + 255) / 256, 256, 0, stream>>>(out_proj, wb_out, n4);
        n4 = VOCAB * D_MODEL / 4;
        cast_kernel<<<(n4 + 255) / 256, 256, 0, stream>>>(fc_w, wb_fc, n4);
        n4 = NLAYERS * D_INNER * DT_RANK / 4;
        cast_kernel<<<(n4 + 255) / 256, 256, 0, stream>>>(dt_w, wb_dt, n4);
        n4 = NLAYERS * XPAD * D_INNER / 4;
        cast_pad_xproj<<<(n4 + 255) / 256, 256, 0, stream>>>(x_proj, wb_x);
    }

    // ---- embedding (fp32 + bf16) ----
    gather_kernel<<<M_ROWS, 256, 0, stream>>>(ids, embed, x, xb);

    for (int i = 0; i < NLAYERS; ++i) {
        const unsigned short* W_in_b  = wb_in + (size_t)i * 2 * D_INNER * D_MODEL;
        const unsigned short* W_out_b = wb_out + (size_t)i * D_MODEL * D_INNER;
        const unsigned short* W_x_b   = wb_x + (size_t)i * XPAD * D_INNER;
        const unsigned short* W_dt_b  = wb_dt + (size_t)i * D_INNER * DT_RANK;
        const float* cw    = conv_w + (size_t)i * D_INNER * 4;
        const float* cb    = conv_b + (size_t)i * D_INNER;
        const float* b_dt  = dt_b + (size_t)i * D_INNER;
        const float* Al    = A_log + (size_t)i * D_INNER * D_STATE;
        const float* Dl    = Dp + (size_t)i * D_INNER;
        const float* g     = ln_g + (size_t)i * D_MODEL;
        const float* bb    = ln_b + (size_t)i * D_MODEL;

        // xz(bf16) = x @ in_proj^T   (2048 x 4096, K=1024)   grid 16x32
        gemm_bf16_nt<1><<<dim3(M_ROWS / 128, 2 * D_INNER / 128), 256, 0, stream>>>(
            xb, D_MODEL, W_in_b, D_MODEL, xzb, 2 * D_INNER, D_MODEL, nullptr);

        // xc(bf16) = silu(conv(xz[:, :2048]) + cb)
        conv_silu_kernel<<<(M_ROWS * D_INNER) / 256, 256, 0, stream>>>(xzb, cw, cb, xcb);

        // x_dbl partials: (2048 x 128, K=2048 split XSK x 128)  grid 16x1x16
        gemm_bf16_nt<0><<<dim3(M_ROWS / 128, 1, XSK), 256, 0, stream>>>(
            xcb, D_INNER, W_x_b, D_INNER, xpart, XPAD, D_INNER / XSK, nullptr);
        reduce_xdbl<<<(M_ROWS * XPAD / 4) / 256, 256, 0, stream>>>(xpart, xdbl, xdbl_b);

        // dt(bf16) = softplus(x_dbl[:, :64] @ dt_w^T + b_dt)  (2048x2048, K=64) grid 16x16
        gemm_bf16_nt<3><<<dim3(M_ROWS / 128, D_INNER / 128), 256, 0, stream>>>(
            xdbl_b, XPAD, W_dt_b, DT_RANK, dtb, D_INNER, DT_RANK, b_dt);

        // chunk-parallel scan -> yb (bf16)
        scan_partial<<<BATCH * NC * (D_INNER / 256), 256, 0, stream>>>(
            dtb, xdbl, xcb, Al, Hbuf, Pbuf);
        scan_combine<<<(BATCH * D_STATE * D_INNER) / 256, 256, 0, stream>>>(Hbuf, Pbuf);
        scan_final<<<BATCH * NC * (D_INNER / 256), 256, 0, stream>>>(
            dtb, xdbl, xcb, xzb, Al, Dl, Pbuf, yb);

        // out_proj partials: (2048 x 1024, K=2048 split 2 x 1024)  grid 16x8x2
        gemm_bf16_nt<0><<<dim3(M_ROWS / 128, D_MODEL / 128, OSK), 256, 0, stream>>>(
            yb, D_INNER, W_out_b, D_INNER, opart, D_MODEL, D_INNER / OSK, nullptr);

        // x = LN(opart0 + opart1 + x)  (fp32 + bf16)
        ln_kernel<2><<<M_ROWS, 256, 0, stream>>>(
            opart, opart + (size_t)M_ROWS * D_MODEL, x, x, xb, g, bb);
    }

    // final LN -> tmp + xb
    ln_kernel<0><<<M_ROWS, 256, 0, stream>>>(nullptr, nullptr, x, tmp, xb, fn_g, fn_b);

    // logits = xf @ fc_w^T + fc_b   (2048 x 32000, K=1024)  8-phase 256² grid 8x125
    gemm_bf16_8ph<<<dim3(M_ROWS / 256, VOCAB / 256), 512, 0, stream>>>(
        xb, D_MODEL, wb_fc, D_MODEL, logits, VOCAB, D_MODEL, fc_b);
}